// Round 6
// baseline (374.098 us; speedup 1.0000x reference)
//
#include <hip/hip_runtime.h>
#include <hip/hip_fp16.h>
#include <cfloat>
#include <cmath>

#define LEAKY 0.2f

typedef _Float16 half8 __attribute__((ext_vector_type(8)));
typedef float f32x4 __attribute__((ext_vector_type(4)));

__device__ __forceinline__ void edge_sd(const int* __restrict__ ei, int e, int E, int& s, int& d) {
    if (e < E) { s = ei[e]; d = ei[E + e]; }
    else       { s = e - E; d = e - E; }   // self loops appended
}

// ---------------- CSR build ----------------
__global__ void hist_k(const int* __restrict__ ei, int E, int ET, int* __restrict__ cnt) {
    int e = blockIdx.x * 256 + threadIdx.x;
    if (e >= ET) return;
    int s, d; edge_sd(ei, e, E, s, d);
    atomicAdd(&cnt[d], 1);
}

__device__ __forceinline__ int wave_incl_scan(int x, int lane) {
#pragma unroll
    for (int off = 1; off < 64; off <<= 1) {
        int y = __shfl_up(x, off);
        if (lane >= off) x += y;
    }
    return x;
}

__global__ __launch_bounds__(1024) void scan_blk_k(const int* __restrict__ cnt,
                                                   int* __restrict__ rowptr,
                                                   int* __restrict__ part, int Nn) {
    __shared__ int wsum[16];
    const int t = threadIdx.x, lane = t & 63, w = t >> 6;
    const int i = blockIdx.x * 1024 + t;
    int v = (i < Nn) ? cnt[i] : 0;
    int sc = wave_incl_scan(v, lane);
    if (lane == 63) wsum[w] = sc;
    __syncthreads();
    if (w == 0 && lane < 16) {
        int x = wsum[lane];
#pragma unroll
        for (int off = 1; off < 16; off <<= 1) {
            int y = __shfl_up(x, off);
            if (lane >= off) x += y;
        }
        wsum[lane] = x;
    }
    __syncthreads();
    int excl = sc - v + (w ? wsum[w - 1] : 0);
    if (i < Nn) rowptr[i] = excl;
    if (t == 1023) part[blockIdx.x] = wsum[15];
}

__global__ __launch_bounds__(128) void scan_part_k(int* __restrict__ part, int nb) {
    __shared__ int sm[128];
    int t = threadIdx.x;
    int v = (t < nb) ? part[t] : 0;
    sm[t] = v; __syncthreads();
    for (int off = 1; off < 128; off <<= 1) {
        int add = (t >= off) ? sm[t - off] : 0;
        __syncthreads();
        sm[t] += add;
        __syncthreads();
    }
    if (t < nb) part[t] = sm[t] - v;
}

__global__ __launch_bounds__(1024) void scan_add_k(int* __restrict__ rowptr,
                                                   const int* __restrict__ part,
                                                   int Nn, int ET) {
    int i = blockIdx.x * 1024 + threadIdx.x;
    if (i < Nn) rowptr[i] += part[blockIdx.x];
    if (i == 0) rowptr[Nn] = ET;
}

__global__ void scatter_k(const int* __restrict__ ei, int E, int ET,
                          const int* __restrict__ rowptr, int* __restrict__ cnt2,
                          int* __restrict__ srcs) {
    int e = blockIdx.x * 256 + threadIdx.x;
    if (e >= ET) return;
    int s, d; edge_sd(ei, e, E, s, d);
    int pos = rowptr[d] + atomicAdd(&cnt2[d], 1);
    srcs[pos] = s;
}

// ---------------- W1 pack into MFMA B-fragment order, fp16 ----------------
__global__ void wpack1_k(const float* __restrict__ W1, _Float16* __restrict__ Wpk) {
    int g = blockIdx.x * 256 + threadIdx.x;
    if (g >= 4096) return;
    int t = g >> 9, s = (g >> 6) & 7, l = g & 63;
    int krow = s * 32 + ((l >> 4) << 3);
    int col = t * 16 + (l & 15);
    half8 v;
#pragma unroll
    for (int j = 0; j < 8; ++j) v[j] = (_Float16)W1[(size_t)(krow + j) * 128 + col];
    *(half8*)&Wpk[(size_t)g * 8] = v;
}

// ---------------- layer1 GEMM via MFMA ----------------
__global__ __launch_bounds__(512) void gemm1_k(const float* __restrict__ x,
                                               const _Float16* __restrict__ Wpk,
                                               _Float16* __restrict__ h1, int Mt) {
    __shared__ __align__(16) _Float16 xs[32 * 256];   // 16 KB, XOR-swizzled
    const int t = threadIdx.x;
    const int l = t & 63;
    const int w = t >> 6;
    const int mstr = w >> 2;
    const int npair = w & 3;

    half8 bf0[8], bf1[8];
#pragma unroll
    for (int s = 0; s < 8; ++s) {
        bf0[s] = *(const half8*)&Wpk[(size_t)(((npair * 2 + 0) * 8 + s) * 64 + l) * 8];
        bf1[s] = *(const half8*)&Wpk[(size_t)(((npair * 2 + 1) * 8 + s) * 64 + l) * 8];
    }

    const int r = t >> 4;
    const int kc = t & 15;
    const int swz = (r & 7) << 4;
    const int arow = mstr * 16 + (l & 15);
    const int aswz = (arow & 7) << 4;
    const int abase = arow * 256;

    for (int mt = blockIdx.x; mt < Mt; mt += gridDim.x) {
        const int mBase = mt * 32;
        const float4* xrow = (const float4*)(x + (size_t)(mBase + r) * 256);
#pragma unroll
        for (int i = 0; i < 4; ++i) {
            float4 v = xrow[kc + i * 16];
            union { _Float16 h[4]; uint2 u; } cv;
            cv.h[0] = (_Float16)v.x; cv.h[1] = (_Float16)v.y;
            cv.h[2] = (_Float16)v.z; cv.h[3] = (_Float16)v.w;
            int kb = kc * 8 + i * 128;
            *(uint2*)&xs[r * 256 + ((kb ^ swz) >> 1)] = cv.u;
        }
        __syncthreads();
        f32x4 acc0 = {0.f, 0.f, 0.f, 0.f}, acc1 = {0.f, 0.f, 0.f, 0.f};
#pragma unroll
        for (int s = 0; s < 8; ++s) {
            int kb = s * 64 + ((l >> 4) << 4);
            half8 a = *(const half8*)&xs[abase + ((kb ^ aswz) >> 1)];
            acc0 = __builtin_amdgcn_mfma_f32_16x16x32_f16(a, bf0[s], acc0, 0, 0, 0);
            acc1 = __builtin_amdgcn_mfma_f32_16x16x32_f16(a, bf1[s], acc1, 0, 0, 0);
        }
        const int drow = mBase + mstr * 16 + ((l >> 4) << 2);
        const int dcol = npair * 32 + (l & 15);
#pragma unroll
        for (int rr = 0; rr < 4; ++rr) {
            h1[(size_t)(drow + rr) * 128 + dcol]      = (_Float16)acc0[rr];
            h1[(size_t)(drow + rr) * 128 + dcol + 16] = (_Float16)acc1[rr];
        }
        __syncthreads();
    }
}

// ---------------- layer1 attention coefficients [N,4] ----------------
__global__ void acoef1_k(const __half* __restrict__ h1, const float* __restrict__ att_s,
                         const float* __restrict__ att_d, float* __restrict__ a1s,
                         float* __restrict__ a1d, int Nn) {
    int g = blockIdx.x * 256 + threadIdx.x;
    if (g >= Nn * 4) return;
    int node = g >> 2, head = g & 3;
    const __half2* hp = (const __half2*)(h1 + (size_t)node * 128 + head * 32);
    const float* as = att_s + head * 32;
    const float* ad = att_d + head * 32;
    float s = 0.0f, d = 0.0f;
#pragma unroll
    for (int c = 0; c < 16; ++c) {
        float2 v = __half22float2(hp[c]);
        s += v.x * as[2 * c] + v.y * as[2 * c + 1];
        d += v.x * ad[2 * c] + v.y * ad[2 * c + 1];
    }
    a1s[g] = s; a1d[g] = d;
}

// ---------------- layer1 fused: softmax + aggregate + bias + ELU + gemm2 + acoef2 ----
// grouped gather: 4 lane-groups x 16 lanes; each group owns an edge, lane loads 16B
__global__ __launch_bounds__(256) void agg1_k(const int* __restrict__ rowptr,
                                              const int* __restrict__ srcs,
                                              const float* __restrict__ a1s,
                                              const float* __restrict__ a1d,
                                              const __half* __restrict__ h1,
                                              const float* __restrict__ b1,
                                              const float* __restrict__ W2,
                                              const float* __restrict__ att_s2,
                                              const float* __restrict__ att_d2,
                                              __half* __restrict__ h2,
                                              float* __restrict__ a2s,
                                              float* __restrict__ a2d, int Nn) {
    __shared__ int   s_s[4][64];
    __shared__ float s_al[4][64][4];
    __shared__ float rowb[4][128];
    __shared__ float w2s[128 * 16];
    const int wv = threadIdx.x >> 6;
    const int lane = threadIdx.x & 63;
    const int n = blockIdx.x * 4 + wv;

    for (int i4 = threadIdx.x; i4 < 512; i4 += 256)
        *(float4*)&w2s[i4 * 4] = *(const float4*)&W2[i4 * 4];

    if (n < Nn) {
        const int beg = rowptr[n], end = rowptr[n + 1];
        const int cnt = end - beg;
        const float4 ad4 = ((const float4*)a1d)[n];

        // ---- window 0: per-lane edge, all 4 heads ----
        int e = beg + lane;
        bool val = e < end;
        int sv = val ? srcs[e] : 0;
        float4 a = ((const float4*)a1s)[sv];
        float v0 = a.x + ad4.x, v1 = a.y + ad4.y, v2 = a.z + ad4.z, v3 = a.w + ad4.w;
        v0 = fmaxf(v0, LEAKY * v0); v1 = fmaxf(v1, LEAKY * v1);
        v2 = fmaxf(v2, LEAKY * v2); v3 = fmaxf(v3, LEAKY * v3);
        float al0 = val ? __expf(v0) : 0.0f, al1 = val ? __expf(v1) : 0.0f;
        float al2 = val ? __expf(v2) : 0.0f, al3 = val ? __expf(v3) : 0.0f;
        float t0 = al0, t1 = al1, t2 = al2, t3 = al3;
        for (int base = beg + 64; base < end; base += 64) {   // rare (deg>64)
            int ee = base + lane; bool vv = ee < end;
            int ss = vv ? srcs[ee] : 0;
            float4 aa = ((const float4*)a1s)[ss];
            float w0 = aa.x + ad4.x, w1 = aa.y + ad4.y, w2v = aa.z + ad4.z, w3 = aa.w + ad4.w;
            w0 = fmaxf(w0, LEAKY * w0); w1 = fmaxf(w1, LEAKY * w1);
            w2v = fmaxf(w2v, LEAKY * w2v); w3 = fmaxf(w3, LEAKY * w3);
            if (vv) { t0 += __expf(w0); t1 += __expf(w1); t2 += __expf(w2v); t3 += __expf(w3); }
        }
#pragma unroll
        for (int off = 1; off < 64; off <<= 1) {
            t0 += __shfl_xor(t0, off); t1 += __shfl_xor(t1, off);
            t2 += __shfl_xor(t2, off); t3 += __shfl_xor(t3, off);
        }
        const float i0 = 1.0f / (t0 + 1e-16f), i1 = 1.0f / (t1 + 1e-16f);
        const float i2 = 1.0f / (t2 + 1e-16f), i3 = 1.0f / (t3 + 1e-16f);

        s_s[wv][lane] = sv;
        *(float4*)&s_al[wv][lane][0] = make_float4(al0 * i0, al1 * i1, al2 * i2, al3 * i3);

        // ---- grouped aggregation ----
        const int g = lane >> 4, u = lane & 15, hg = u >> 2;
        const size_t coff = (size_t)u * 8;
        float facc[8];
#pragma unroll
        for (int j = 0; j < 8; ++j) facc[j] = 0.0f;

        int wcnt = cnt < 64 ? cnt : 64;
        int kq = (wcnt + 3) & ~3;
        int ko = 0;
        for (; ko + 8 <= kq; ko += 8) {           // 2 quads in flight
            int sA = s_s[wv][ko + g],     sB = s_s[wv][ko + 4 + g];
            float pA = s_al[wv][ko + g][hg], pB = s_al[wv][ko + 4 + g][hg];
            float4 rA = *(const float4*)&h1[(size_t)sA * 128 + coff];
            float4 rB = *(const float4*)&h1[(size_t)sB * 128 + coff];
            __half2* hA = (__half2*)&rA;
            __half2* hB = (__half2*)&rB;
#pragma unroll
            for (int q = 0; q < 4; ++q) {
                float2 fA = __half22float2(hA[q]);
                float2 fB = __half22float2(hB[q]);
                facc[2 * q]     = fmaf(pA, fA.x, facc[2 * q]);
                facc[2 * q + 1] = fmaf(pA, fA.y, facc[2 * q + 1]);
                facc[2 * q]     = fmaf(pB, fB.x, facc[2 * q]);
                facc[2 * q + 1] = fmaf(pB, fB.y, facc[2 * q + 1]);
            }
        }
        if (ko < kq) {
            int sA = s_s[wv][ko + g];
            float pA = s_al[wv][ko + g][hg];
            float4 rA = *(const float4*)&h1[(size_t)sA * 128 + coff];
            __half2* hA = (__half2*)&rA;
#pragma unroll
            for (int q = 0; q < 4; ++q) {
                float2 fA = __half22float2(hA[q]);
                facc[2 * q]     = fmaf(pA, fA.x, facc[2 * q]);
                facc[2 * q + 1] = fmaf(pA, fA.y, facc[2 * q + 1]);
            }
        }
        for (int base = beg + 64; base < end; base += 64) {   // rare (deg>64)
            int ee = base + lane; bool vv = ee < end;
            int ss = vv ? srcs[ee] : 0;
            float4 aa = ((const float4*)a1s)[ss];
            float w0 = aa.x + ad4.x, w1 = aa.y + ad4.y, w2v = aa.z + ad4.z, w3 = aa.w + ad4.w;
            w0 = fmaxf(w0, LEAKY * w0); w1 = fmaxf(w1, LEAKY * w1);
            w2v = fmaxf(w2v, LEAKY * w2v); w3 = fmaxf(w3, LEAKY * w3);
            s_s[wv][lane] = ss;
            *(float4*)&s_al[wv][lane][0] = make_float4(
                vv ? __expf(w0) * i0 : 0.0f, vv ? __expf(w1) * i1 : 0.0f,
                vv ? __expf(w2v) * i2 : 0.0f, vv ? __expf(w3) * i3 : 0.0f);
            int wc = end - base; if (wc > 64) wc = 64;
            int kq2 = (wc + 3) & ~3;
            for (int k2 = 0; k2 < kq2; k2 += 4) {
                int sA = s_s[wv][k2 + g];
                float pA = s_al[wv][k2 + g][hg];
                float4 rA = *(const float4*)&h1[(size_t)sA * 128 + coff];
                __half2* hA = (__half2*)&rA;
#pragma unroll
                for (int q = 0; q < 4; ++q) {
                    float2 fA = __half22float2(hA[q]);
                    facc[2 * q]     = fmaf(pA, fA.x, facc[2 * q]);
                    facc[2 * q + 1] = fmaf(pA, fA.y, facc[2 * q + 1]);
                }
            }
        }
        // reduce across 4 groups
#pragma unroll
        for (int j = 0; j < 8; ++j) {
            facc[j] += __shfl_xor(facc[j], 16);
            facc[j] += __shfl_xor(facc[j], 32);
        }
        if (g == 0) {
            float4 bb0 = *(const float4*)&b1[u * 8];
            float4 bb1 = *(const float4*)&b1[u * 8 + 4];
            float o[8] = { facc[0] + bb0.x, facc[1] + bb0.y, facc[2] + bb0.z, facc[3] + bb0.w,
                           facc[4] + bb1.x, facc[5] + bb1.y, facc[6] + bb1.z, facc[7] + bb1.w };
#pragma unroll
            for (int j = 0; j < 8; ++j) {
                float oj = o[j];
                rowb[wv][u * 8 + j] = oj > 0.0f ? oj : expm1f(oj);
            }
        }
    }
    __syncthreads();
    if (n >= Nn) return;

    // fused layer2 GEMM row; k = kk*4+q ordering -> bank-conflict-free
    const int q = lane >> 4, j = lane & 15;
    const float* rb = rowb[wv];
    float part = 0.0f;
#pragma unroll
    for (int kk = 0; kk < 32; ++kk) {
        int k = kk * 4 + q;
        part = fmaf(rb[k], w2s[k * 16 + j], part);
    }
    part += __shfl_xor(part, 16);
    part += __shfl_xor(part, 32);
    float vs = part * att_s2[j];
    float vd = part * att_d2[j];
#pragma unroll
    for (int off = 1; off < 16; off <<= 1) {
        vs += __shfl_xor(vs, off);
        vd += __shfl_xor(vd, off);
    }
    if (lane < 16) h2[(size_t)n * 16 + j] = __float2half(part);
    if (lane == 0) { a2s[n] = vs; a2d[n] = vd; }
}

// ---------------- layer2 fused softmax + aggregate + bias ----------------
// grouped gather: 8 lane-groups x 8 lanes; lane loads half2 (4B)
__global__ __launch_bounds__(256) void agg2_k(const int* __restrict__ rowptr,
                                              const int* __restrict__ srcs,
                                              const float* __restrict__ a2s,
                                              const float* __restrict__ a2d,
                                              const __half* __restrict__ h2,
                                              const float* __restrict__ b2,
                                              float* __restrict__ dout, int Nn) {
    __shared__ int   s_s[4][64];
    __shared__ float s_al[4][64];
    const int wv = threadIdx.x >> 6;
    const int lane = threadIdx.x & 63;
    const int n = blockIdx.x * 4 + wv;
    if (n >= Nn) return;
    const int beg = rowptr[n], end = rowptr[n + 1];
    const int cnt = end - beg;
    const float adn = a2d[n];

    int e = beg + lane;
    bool val = e < end;
    int sv = val ? srcs[e] : 0;
    float av = a2s[sv] + adn;
    av = fmaxf(av, LEAKY * av);
    float al = val ? __expf(av) : 0.0f;
    float ss = al;
    for (int base = beg + 64; base < end; base += 64) {
        int ee = base + lane; bool vv = ee < end;
        float aw = a2s[vv ? srcs[ee] : 0] + adn;
        aw = fmaxf(aw, LEAKY * aw);
        if (vv) ss += __expf(aw);
    }
#pragma unroll
    for (int off = 1; off < 64; off <<= 1) ss += __shfl_xor(ss, off);
    const float sinv = 1.0f / (ss + 1e-16f);

    s_s[wv][lane] = sv;
    s_al[wv][lane] = al * sinv;

    const int g = lane >> 3, u = lane & 7;
    float f0 = 0.0f, f1 = 0.0f;
    int wcnt = cnt < 64 ? cnt : 64;
    int kq = (wcnt + 7) & ~7;
    int ko = 0;
    for (; ko + 16 <= kq; ko += 16) {
        int sA = s_s[wv][ko + g], sB = s_s[wv][ko + 8 + g];
        float pA = s_al[wv][ko + g], pB = s_al[wv][ko + 8 + g];
        float2 fA = __half22float2(*(const __half2*)&h2[(size_t)sA * 16 + u * 2]);
        float2 fB = __half22float2(*(const __half2*)&h2[(size_t)sB * 16 + u * 2]);
        f0 = fmaf(pA, fA.x, f0); f1 = fmaf(pA, fA.y, f1);
        f0 = fmaf(pB, fB.x, f0); f1 = fmaf(pB, fB.y, f1);
    }
    if (ko < kq) {
        int sA = s_s[wv][ko + g];
        float pA = s_al[wv][ko + g];
        float2 fA = __half22float2(*(const __half2*)&h2[(size_t)sA * 16 + u * 2]);
        f0 = fmaf(pA, fA.x, f0); f1 = fmaf(pA, fA.y, f1);
    }
    for (int base = beg + 64; base < end; base += 64) {
        int ee = base + lane; bool vv = ee < end;
        int sn = vv ? srcs[ee] : 0;
        float aw = a2s[sn] + adn;
        aw = fmaxf(aw, LEAKY * aw);
        s_s[wv][lane] = sn;
        s_al[wv][lane] = vv ? __expf(aw) * sinv : 0.0f;
        int wc = end - base; if (wc > 64) wc = 64;
        int kq2 = (wc + 7) & ~7;
        for (int k2 = 0; k2 < kq2; k2 += 8) {
            int sA = s_s[wv][k2 + g];
            float pA = s_al[wv][k2 + g];
            float2 fA = __half22float2(*(const __half2*)&h2[(size_t)sA * 16 + u * 2]);
            f0 = fmaf(pA, fA.x, f0); f1 = fmaf(pA, fA.y, f1);
        }
    }
#pragma unroll
    for (int off = 8; off < 64; off <<= 1) {
        f0 += __shfl_xor(f0, off);
        f1 += __shfl_xor(f1, off);
    }
    if (g == 0) {
        float2 bb = *(const float2*)&b2[u * 2];
        *(float2*)&dout[(size_t)n * 16 + u * 2] = make_float2(f0 + bb.x, f1 + bb.y);
    }
}

extern "C" void kernel_launch(void* const* d_in, const int* in_sizes, int n_in,
                              void* d_out, int out_size, void* d_ws, size_t ws_size,
                              hipStream_t stream) {
    const float* x      = (const float*)d_in[0];
    const int*   ei     = (const int*)d_in[1];
    const float* W1     = (const float*)d_in[2];
    const float* att_s1 = (const float*)d_in[3];
    const float* att_d1 = (const float*)d_in[4];
    const float* b1     = (const float*)d_in[5];
    const float* W2     = (const float*)d_in[6];
    const float* att_s2 = (const float*)d_in[7];
    const float* att_d2 = (const float*)d_in[8];
    const float* b2     = (const float*)d_in[9];
    float* dout = (float*)d_out;

    const int Nn = in_sizes[0] / 256;     // 100000
    const int E  = in_sizes[1] / 2;       // 1600000
    const int ET = E + Nn;

    char* p = (char*)d_ws;
    auto alloc = [&](size_t bytes) { char* r = p; p += (bytes + 255) & ~(size_t)255; return r; };
    _Float16* h1  = (_Float16*)alloc((size_t)Nn * 128 * 2);
    __half* h2    = (__half*)alloc((size_t)Nn * 16 * 2);
    _Float16* Wpk = (_Float16*)alloc(4096 * 8 * 2);
    float* a1s    = (float*)alloc((size_t)Nn * 4 * 4);
    float* a1d    = (float*)alloc((size_t)Nn * 4 * 4);
    float* a2s    = (float*)alloc((size_t)Nn * 4);
    float* a2d    = (float*)alloc((size_t)Nn * 4);
    int* rowptr   = (int*)alloc((size_t)(Nn + 1) * 4);
    char* zbase   = p;                                  // contiguous zero region
    int* cnt      = (int*)alloc((size_t)Nn * 4);
    int* cnt2     = (int*)alloc((size_t)Nn * 4);
    size_t zlen   = (size_t)(p - zbase);
    int* part     = (int*)alloc(128 * 4);
    int* srcs     = (int*)alloc((size_t)ET * 4);

    const int nbScan = (Nn + 1023) / 1024;

    // CSR build
    hipMemsetAsync(zbase, 0, zlen, stream);
    hist_k<<<dim3((ET + 255) / 256), dim3(256), 0, stream>>>(ei, E, ET, cnt);
    scan_blk_k<<<dim3(nbScan), dim3(1024), 0, stream>>>(cnt, rowptr, part, Nn);
    scan_part_k<<<dim3(1), dim3(128), 0, stream>>>(part, nbScan);
    scan_add_k<<<dim3(nbScan), dim3(1024), 0, stream>>>(rowptr, part, Nn, ET);
    scatter_k<<<dim3((ET + 255) / 256), dim3(256), 0, stream>>>(ei, E, ET, rowptr, cnt2, srcs);
    // layer 1
    wpack1_k<<<dim3(16), dim3(256), 0, stream>>>(W1, Wpk);
    gemm1_k<<<dim3(512), dim3(512), 0, stream>>>(x, Wpk, h1, Nn / 32);
    acoef1_k<<<dim3((Nn * 4 + 255) / 256), dim3(256), 0, stream>>>((const __half*)h1, att_s1, att_d1, a1s, a1d, Nn);
    // fused agg1 + gemm2 + acoef2
    agg1_k<<<dim3((Nn + 3) / 4), dim3(256), 0, stream>>>(rowptr, srcs, a1s, a1d,
                                                         (const __half*)h1, b1,
                                                         W2, att_s2, att_d2,
                                                         h2, a2s, a2d, Nn);
    // layer 2 aggregation
    agg2_k<<<dim3((Nn + 3) / 4), dim3(256), 0, stream>>>(rowptr, srcs, a2s, a2d, h2, b2, dout, Nn);
}

// Round 7
// 290.054 us; speedup vs baseline: 1.2898x; 1.2898x over previous
//
#include <hip/hip_runtime.h>
#include <hip/hip_fp16.h>
#include <cfloat>
#include <cmath>

#define LEAKY 0.2f

typedef _Float16 half8 __attribute__((ext_vector_type(8)));
typedef float f32x4 __attribute__((ext_vector_type(4)));

__device__ __forceinline__ void edge_sd(const int* __restrict__ ei, int e, int E, int& s, int& d) {
    if (e < E) { s = ei[e]; d = ei[E + e]; }
    else       { s = e - E; d = e - E; }   // self loops appended
}

// ---------------- CSR build: hist with rank capture ----------------
__global__ void hist_k(const int* __restrict__ ei, int E, int ET,
                       int* __restrict__ cnt, int* __restrict__ rank) {
    int e = blockIdx.x * 256 + threadIdx.x;
    if (e >= ET) return;
    int d = (e < E) ? ei[E + e] : e - E;
    rank[e] = atomicAdd(&cnt[d], 1);
}

__device__ __forceinline__ int wave_incl_scan(int x, int lane) {
#pragma unroll
    for (int off = 1; off < 64; off <<= 1) {
        int y = __shfl_up(x, off);
        if (lane >= off) x += y;
    }
    return x;
}

__global__ __launch_bounds__(1024) void scan_blk_k(const int* __restrict__ cnt,
                                                   int* __restrict__ rowptr,
                                                   int* __restrict__ part, int Nn) {
    __shared__ int wsum[16];
    const int t = threadIdx.x, lane = t & 63, w = t >> 6;
    const int i = blockIdx.x * 1024 + t;
    int v = (i < Nn) ? cnt[i] : 0;
    int sc = wave_incl_scan(v, lane);
    if (lane == 63) wsum[w] = sc;
    __syncthreads();
    if (w == 0 && lane < 16) {
        int x = wsum[lane];
#pragma unroll
        for (int off = 1; off < 16; off <<= 1) {
            int y = __shfl_up(x, off);
            if (lane >= off) x += y;
        }
        wsum[lane] = x;
    }
    __syncthreads();
    int excl = sc - v + (w ? wsum[w - 1] : 0);
    if (i < Nn) rowptr[i] = excl;
    if (t == 1023) part[blockIdx.x] = wsum[15];
}

__global__ __launch_bounds__(128) void scan_part_k(int* __restrict__ part, int nb) {
    __shared__ int sm[128];
    int t = threadIdx.x;
    int v = (t < nb) ? part[t] : 0;
    sm[t] = v; __syncthreads();
    for (int off = 1; off < 128; off <<= 1) {
        int add = (t >= off) ? sm[t - off] : 0;
        __syncthreads();
        sm[t] += add;
        __syncthreads();
    }
    if (t < nb) part[t] = sm[t] - v;
}

__global__ __launch_bounds__(1024) void scan_add_k(int* __restrict__ rowptr,
                                                   const int* __restrict__ part,
                                                   int Nn, int ET) {
    int i = blockIdx.x * 1024 + threadIdx.x;
    if (i < Nn) rowptr[i] += part[blockIdx.x];
    if (i == 0) rowptr[Nn] = ET;
}

// no atomic: pos = rowptr[d] + rank[e]
__global__ void scatter_k(const int* __restrict__ ei, int E, int ET,
                          const int* __restrict__ rowptr, const int* __restrict__ rank,
                          int* __restrict__ srcs) {
    int e = blockIdx.x * 256 + threadIdx.x;
    if (e >= ET) return;
    int s, d; edge_sd(ei, e, E, s, d);
    srcs[rowptr[d] + rank[e]] = s;
}

// ---------------- W1 pack into MFMA B-fragment order, fp16 ----------------
__global__ void wpack1_k(const float* __restrict__ W1, _Float16* __restrict__ Wpk) {
    int g = blockIdx.x * 256 + threadIdx.x;
    if (g >= 4096) return;
    int t = g >> 9, s = (g >> 6) & 7, l = g & 63;
    int krow = s * 32 + ((l >> 4) << 3);
    int col = t * 16 + (l & 15);
    half8 v;
#pragma unroll
    for (int j = 0; j < 8; ++j) v[j] = (_Float16)W1[(size_t)(krow + j) * 128 + col];
    *(half8*)&Wpk[(size_t)g * 8] = v;
}

// ---------------- layer1 GEMM via MFMA ----------------
__global__ __launch_bounds__(512) void gemm1_k(const float* __restrict__ x,
                                               const _Float16* __restrict__ Wpk,
                                               _Float16* __restrict__ h1, int Mt) {
    __shared__ __align__(16) _Float16 xs[32 * 256];   // 16 KB, XOR-swizzled
    const int t = threadIdx.x;
    const int l = t & 63;
    const int w = t >> 6;
    const int mstr = w >> 2;
    const int npair = w & 3;

    half8 bf0[8], bf1[8];
#pragma unroll
    for (int s = 0; s < 8; ++s) {
        bf0[s] = *(const half8*)&Wpk[(size_t)(((npair * 2 + 0) * 8 + s) * 64 + l) * 8];
        bf1[s] = *(const half8*)&Wpk[(size_t)(((npair * 2 + 1) * 8 + s) * 64 + l) * 8];
    }

    const int r = t >> 4;
    const int kc = t & 15;
    const int swz = (r & 7) << 4;
    const int arow = mstr * 16 + (l & 15);
    const int aswz = (arow & 7) << 4;
    const int abase = arow * 256;

    for (int mt = blockIdx.x; mt < Mt; mt += gridDim.x) {
        const int mBase = mt * 32;
        const float4* xrow = (const float4*)(x + (size_t)(mBase + r) * 256);
#pragma unroll
        for (int i = 0; i < 4; ++i) {
            float4 v = xrow[kc + i * 16];
            union { _Float16 h[4]; uint2 u; } cv;
            cv.h[0] = (_Float16)v.x; cv.h[1] = (_Float16)v.y;
            cv.h[2] = (_Float16)v.z; cv.h[3] = (_Float16)v.w;
            int kb = kc * 8 + i * 128;
            *(uint2*)&xs[r * 256 + ((kb ^ swz) >> 1)] = cv.u;
        }
        __syncthreads();
        f32x4 acc0 = {0.f, 0.f, 0.f, 0.f}, acc1 = {0.f, 0.f, 0.f, 0.f};
#pragma unroll
        for (int s = 0; s < 8; ++s) {
            int kb = s * 64 + ((l >> 4) << 4);
            half8 a = *(const half8*)&xs[abase + ((kb ^ aswz) >> 1)];
            acc0 = __builtin_amdgcn_mfma_f32_16x16x32_f16(a, bf0[s], acc0, 0, 0, 0);
            acc1 = __builtin_amdgcn_mfma_f32_16x16x32_f16(a, bf1[s], acc1, 0, 0, 0);
        }
        const int drow = mBase + mstr * 16 + ((l >> 4) << 2);
        const int dcol = npair * 32 + (l & 15);
#pragma unroll
        for (int rr = 0; rr < 4; ++rr) {
            h1[(size_t)(drow + rr) * 128 + dcol]      = (_Float16)acc0[rr];
            h1[(size_t)(drow + rr) * 128 + dcol + 16] = (_Float16)acc1[rr];
        }
        __syncthreads();
    }
}

// ---------------- layer1 attention coefficients [N,4] ----------------
__global__ void acoef1_k(const __half* __restrict__ h1, const float* __restrict__ att_s,
                         const float* __restrict__ att_d, float* __restrict__ a1s,
                         float* __restrict__ a1d, int Nn) {
    int g = blockIdx.x * 256 + threadIdx.x;
    if (g >= Nn * 4) return;
    int node = g >> 2, head = g & 3;
    const __half2* hp = (const __half2*)(h1 + (size_t)node * 128 + head * 32);
    const float* as = att_s + head * 32;
    const float* ad = att_d + head * 32;
    float s = 0.0f, d = 0.0f;
#pragma unroll
    for (int c = 0; c < 16; ++c) {
        float2 v = __half22float2(hp[c]);
        s += v.x * as[2 * c] + v.y * as[2 * c + 1];
        d += v.x * ad[2 * c] + v.y * ad[2 * c + 1];
    }
    a1s[g] = s; a1d[g] = d;
}

// ---------------- layer1 fused: softmax + aggregate + bias + ELU + gemm2 + acoef2 ----
// one 64-lane wave per destination node (R5 structure)
__global__ __launch_bounds__(256) void agg1_k(const int* __restrict__ rowptr,
                                              const int* __restrict__ srcs,
                                              const float* __restrict__ a1s,
                                              const float* __restrict__ a1d,
                                              const __half* __restrict__ h1,
                                              const float* __restrict__ b1,
                                              const float* __restrict__ W2,
                                              const float* __restrict__ att_s2,
                                              const float* __restrict__ att_d2,
                                              __half* __restrict__ h2,
                                              float* __restrict__ a2s,
                                              float* __restrict__ a2d, int Nn) {
    __shared__ int   s_s[4][64];
    __shared__ float s_al[4][64][4];
    __shared__ float rowb[4][128];
    __shared__ float w2s[128 * 16];
    const int wv = threadIdx.x >> 6;
    const int lane = threadIdx.x & 63;
    const int n = blockIdx.x * 4 + wv;

    for (int i4 = threadIdx.x; i4 < 512; i4 += 256)
        *(float4*)&w2s[i4 * 4] = *(const float4*)&W2[i4 * 4];

    if (n < Nn) {
        const int beg = rowptr[n], end = rowptr[n + 1];
        const int cnt = end - beg;
        const float4 ad4 = ((const float4*)a1d)[n];

        int e = beg + lane;
        bool val = e < end;
        int sv = val ? srcs[e] : 0;
        float4 a = ((const float4*)a1s)[sv];
        float v0 = a.x + ad4.x, v1 = a.y + ad4.y, v2 = a.z + ad4.z, v3 = a.w + ad4.w;
        v0 = fmaxf(v0, LEAKY * v0); v1 = fmaxf(v1, LEAKY * v1);
        v2 = fmaxf(v2, LEAKY * v2); v3 = fmaxf(v3, LEAKY * v3);
        float al0 = val ? __expf(v0) : 0.0f, al1 = val ? __expf(v1) : 0.0f;
        float al2 = val ? __expf(v2) : 0.0f, al3 = val ? __expf(v3) : 0.0f;
        float t0 = al0, t1 = al1, t2 = al2, t3 = al3;
        for (int base = beg + 64; base < end; base += 64) {   // rare (deg>64)
            int ee = base + lane; bool vv = ee < end;
            int ss = vv ? srcs[ee] : 0;
            float4 aa = ((const float4*)a1s)[ss];
            float w0 = aa.x + ad4.x, w1 = aa.y + ad4.y, w2v = aa.z + ad4.z, w3 = aa.w + ad4.w;
            w0 = fmaxf(w0, LEAKY * w0); w1 = fmaxf(w1, LEAKY * w1);
            w2v = fmaxf(w2v, LEAKY * w2v); w3 = fmaxf(w3, LEAKY * w3);
            if (vv) { t0 += __expf(w0); t1 += __expf(w1); t2 += __expf(w2v); t3 += __expf(w3); }
        }
#pragma unroll
        for (int off = 1; off < 64; off <<= 1) {
            t0 += __shfl_xor(t0, off); t1 += __shfl_xor(t1, off);
            t2 += __shfl_xor(t2, off); t3 += __shfl_xor(t3, off);
        }
        const float i0 = 1.0f / (t0 + 1e-16f), i1 = 1.0f / (t1 + 1e-16f);
        const float i2 = 1.0f / (t2 + 1e-16f), i3 = 1.0f / (t3 + 1e-16f);

        const int hc = lane >> 4;
        float2 acc = make_float2(0.0f, 0.0f);
        const size_t lo = 2 * lane;

        s_s[wv][lane] = sv;
        s_al[wv][lane][0] = al0 * i0; s_al[wv][lane][1] = al1 * i1;
        s_al[wv][lane][2] = al2 * i2; s_al[wv][lane][3] = al3 * i3;
        int wcnt = cnt < 64 ? cnt : 64;
        int ko = 0;
        // 4-wide ILP: 4 independent h1-row gathers in flight
        for (; ko + 4 <= wcnt; ko += 4) {
            int s0 = s_s[wv][ko+0], s1 = s_s[wv][ko+1];
            int s2 = s_s[wv][ko+2], s3 = s_s[wv][ko+3];
            float p0 = s_al[wv][ko+0][hc], p1 = s_al[wv][ko+1][hc];
            float p2 = s_al[wv][ko+2][hc], p3 = s_al[wv][ko+3][hc];
            float2 g0 = __half22float2(*(const __half2*)&h1[(size_t)s0 * 128 + lo]);
            float2 g1 = __half22float2(*(const __half2*)&h1[(size_t)s1 * 128 + lo]);
            float2 g2 = __half22float2(*(const __half2*)&h1[(size_t)s2 * 128 + lo]);
            float2 g3 = __half22float2(*(const __half2*)&h1[(size_t)s3 * 128 + lo]);
            acc.x = fmaf(p0, g0.x, acc.x); acc.y = fmaf(p0, g0.y, acc.y);
            acc.x = fmaf(p1, g1.x, acc.x); acc.y = fmaf(p1, g1.y, acc.y);
            acc.x = fmaf(p2, g2.x, acc.x); acc.y = fmaf(p2, g2.y, acc.y);
            acc.x = fmaf(p3, g3.x, acc.x); acc.y = fmaf(p3, g3.y, acc.y);
        }
        for (; ko < wcnt; ++ko) {
            int s = s_s[wv][ko];
            float p = s_al[wv][ko][hc];
            float2 g = __half22float2(*(const __half2*)&h1[(size_t)s * 128 + lo]);
            acc.x = fmaf(p, g.x, acc.x); acc.y = fmaf(p, g.y, acc.y);
        }
        for (int base = beg + 64; base < end; base += 64) {   // rare
            int ee = base + lane; bool vv = ee < end;
            int ss = vv ? srcs[ee] : 0;
            float4 aa = ((const float4*)a1s)[ss];
            float w0 = aa.x + ad4.x, w1 = aa.y + ad4.y, w2v = aa.z + ad4.z, w3 = aa.w + ad4.w;
            w0 = fmaxf(w0, LEAKY * w0); w1 = fmaxf(w1, LEAKY * w1);
            w2v = fmaxf(w2v, LEAKY * w2v); w3 = fmaxf(w3, LEAKY * w3);
            s_s[wv][lane] = ss;
            s_al[wv][lane][0] = vv ? __expf(w0) * i0 : 0.0f;
            s_al[wv][lane][1] = vv ? __expf(w1) * i1 : 0.0f;
            s_al[wv][lane][2] = vv ? __expf(w2v) * i2 : 0.0f;
            s_al[wv][lane][3] = vv ? __expf(w3) * i3 : 0.0f;
            int wc = end - base; if (wc > 64) wc = 64;
            for (int k2 = 0; k2 < wc; ++k2) {
                int s = s_s[wv][k2];
                float p = s_al[wv][k2][hc];
                float2 g = __half22float2(*(const __half2*)&h1[(size_t)s * 128 + lo]);
                acc.x = fmaf(p, g.x, acc.x); acc.y = fmaf(p, g.y, acc.y);
            }
        }
        float2 bb = *(const float2*)&b1[2 * lane];
        float ox = acc.x + bb.x, oy = acc.y + bb.y;
        ox = ox > 0.0f ? ox : expm1f(ox);                 // ELU
        oy = oy > 0.0f ? oy : expm1f(oy);
        rowb[wv][2 * lane] = ox;
        rowb[wv][2 * lane + 1] = oy;
    }
    __syncthreads();
    if (n >= Nn) return;

    // fused layer2 GEMM row; k = kk*4+q ordering -> bank-conflict-free
    const int q = lane >> 4, j = lane & 15;
    const float* rb = rowb[wv];
    float part = 0.0f;
#pragma unroll
    for (int kk = 0; kk < 32; ++kk) {
        int k = kk * 4 + q;
        part = fmaf(rb[k], w2s[k * 16 + j], part);
    }
    part += __shfl_xor(part, 16);
    part += __shfl_xor(part, 32);
    float vs = part * att_s2[j];
    float vd = part * att_d2[j];
#pragma unroll
    for (int off = 1; off < 16; off <<= 1) {
        vs += __shfl_xor(vs, off);
        vd += __shfl_xor(vd, off);
    }
    if (lane < 16) h2[(size_t)n * 16 + j] = __float2half(part);
    if (lane == 0) { a2s[n] = vs; a2d[n] = vd; }
}

// ---------------- layer2 fused softmax + aggregate + bias (R5 structure) ----------------
__global__ __launch_bounds__(256) void agg2_k(const int* __restrict__ rowptr,
                                              const int* __restrict__ srcs,
                                              const float* __restrict__ a2s,
                                              const float* __restrict__ a2d,
                                              const __half* __restrict__ h2,
                                              const float* __restrict__ b2,
                                              float* __restrict__ dout, int Nn) {
    __shared__ int   s_s[4][64];
    __shared__ float s_al[4][64];
    const int wv = threadIdx.x >> 6;
    const int lane = threadIdx.x & 63;
    const int n = blockIdx.x * 4 + wv;
    if (n >= Nn) return;
    const int beg = rowptr[n], end = rowptr[n + 1];
    const int cnt = end - beg;
    const float adn = a2d[n];

    int e = beg + lane;
    bool val = e < end;
    int sv = val ? srcs[e] : 0;
    float av = a2s[sv] + adn;
    av = fmaxf(av, LEAKY * av);
    float al = val ? __expf(av) : 0.0f;
    float ss = al;
    for (int base = beg + 64; base < end; base += 64) {
        int ee = base + lane; bool vv = ee < end;
        float aw = a2s[vv ? srcs[ee] : 0] + adn;
        aw = fmaxf(aw, LEAKY * aw);
        if (vv) ss += __expf(aw);
    }
#pragma unroll
    for (int off = 1; off < 64; off <<= 1) ss += __shfl_xor(ss, off);
    const float sinv = 1.0f / (ss + 1e-16f);

    const int eg = lane >> 4, j = lane & 15;
    float acc = 0.0f;
    s_s[wv][lane] = sv;
    s_al[wv][lane] = al * sinv;
    int wcnt = cnt < 64 ? cnt : 64;
    int ko = eg;
    for (; ko + 4 < wcnt; ko += 8) {        // 2-wide ILP per group
        int s0 = s_s[wv][ko], s1 = s_s[wv][ko + 4];
        float p0 = s_al[wv][ko], p1 = s_al[wv][ko + 4];
        float g0 = __half2float(h2[(size_t)s0 * 16 + j]);
        float g1 = __half2float(h2[(size_t)s1 * 16 + j]);
        acc = fmaf(p0, g0, acc);
        acc = fmaf(p1, g1, acc);
    }
    for (; ko < wcnt; ko += 4) {
        acc = fmaf(s_al[wv][ko], __half2float(h2[(size_t)s_s[wv][ko] * 16 + j]), acc);
    }
    for (int base = beg + 64; base < end; base += 64) {
        int ee = base + lane; bool vv = ee < end;
        int sn = vv ? srcs[ee] : 0;
        float aw = a2s[sn] + adn;
        aw = fmaxf(aw, LEAKY * aw);
        s_s[wv][lane] = sn;
        s_al[wv][lane] = vv ? __expf(aw) * sinv : 0.0f;
        int wc = end - base; if (wc > 64) wc = 64;
        for (int k2 = eg; k2 < wc; k2 += 4) {
            acc = fmaf(s_al[wv][k2], __half2float(h2[(size_t)s_s[wv][k2] * 16 + j]), acc);
        }
    }
    acc += __shfl_xor(acc, 16);
    acc += __shfl_xor(acc, 32);
    if (lane < 16) dout[(size_t)n * 16 + j] = acc + b2[j];
}

extern "C" void kernel_launch(void* const* d_in, const int* in_sizes, int n_in,
                              void* d_out, int out_size, void* d_ws, size_t ws_size,
                              hipStream_t stream) {
    const float* x      = (const float*)d_in[0];
    const int*   ei     = (const int*)d_in[1];
    const float* W1     = (const float*)d_in[2];
    const float* att_s1 = (const float*)d_in[3];
    const float* att_d1 = (const float*)d_in[4];
    const float* b1     = (const float*)d_in[5];
    const float* W2     = (const float*)d_in[6];
    const float* att_s2 = (const float*)d_in[7];
    const float* att_d2 = (const float*)d_in[8];
    const float* b2     = (const float*)d_in[9];
    float* dout = (float*)d_out;

    const int Nn = in_sizes[0] / 256;     // 100000
    const int E  = in_sizes[1] / 2;       // 1600000
    const int ET = E + Nn;

    char* p = (char*)d_ws;
    auto alloc = [&](size_t bytes) { char* r = p; p += (bytes + 255) & ~(size_t)255; return r; };
    _Float16* h1  = (_Float16*)alloc((size_t)Nn * 128 * 2);
    __half* h2    = (__half*)alloc((size_t)Nn * 16 * 2);
    _Float16* Wpk = (_Float16*)alloc(4096 * 8 * 2);
    float* a1s    = (float*)alloc((size_t)Nn * 4 * 4);
    float* a1d    = (float*)alloc((size_t)Nn * 4 * 4);
    float* a2s    = (float*)alloc((size_t)Nn * 4);
    float* a2d    = (float*)alloc((size_t)Nn * 4);
    int* rowptr   = (int*)alloc((size_t)(Nn + 1) * 4);
    int* cnt      = (int*)alloc((size_t)Nn * 4);
    int* rank     = (int*)alloc((size_t)ET * 4);
    int* part     = (int*)alloc(128 * 4);
    int* srcs     = (int*)alloc((size_t)ET * 4);

    const int nbScan = (Nn + 1023) / 1024;

    // CSR build (rank-capture: scatter needs no atomics)
    hipMemsetAsync(cnt, 0, (size_t)Nn * 4, stream);
    hist_k<<<dim3((ET + 255) / 256), dim3(256), 0, stream>>>(ei, E, ET, cnt, rank);
    scan_blk_k<<<dim3(nbScan), dim3(1024), 0, stream>>>(cnt, rowptr, part, Nn);
    scan_part_k<<<dim3(1), dim3(128), 0, stream>>>(part, nbScan);
    scan_add_k<<<dim3(nbScan), dim3(1024), 0, stream>>>(rowptr, part, Nn, ET);
    scatter_k<<<dim3((ET + 255) / 256), dim3(256), 0, stream>>>(ei, E, ET, rowptr, rank, srcs);
    // layer 1
    wpack1_k<<<dim3(16), dim3(256), 0, stream>>>(W1, Wpk);
    gemm1_k<<<dim3(512), dim3(512), 0, stream>>>(x, Wpk, h1, Nn / 32);
    acoef1_k<<<dim3((Nn * 4 + 255) / 256), dim3(256), 0, stream>>>((const __half*)h1, att_s1, att_d1, a1s, a1d, Nn);
    // fused agg1 + gemm2 + acoef2
    agg1_k<<<dim3((Nn + 3) / 4), dim3(256), 0, stream>>>(rowptr, srcs, a1s, a1d,
                                                         (const __half*)h1, b1,
                                                         W2, att_s2, att_d2,
                                                         h2, a2s, a2d, Nn);
    // layer 2 aggregation
    agg2_k<<<dim3((Nn + 3) / 4), dim3(256), 0, stream>>>(rowptr, srcs, a2s, a2d, h2, b2, dout, Nn);
}

// Round 8
// 280.199 us; speedup vs baseline: 1.3351x; 1.0352x over previous
//
#include <hip/hip_runtime.h>
#include <hip/hip_fp16.h>
#include <cfloat>
#include <cmath>

#define LEAKY 0.2f

typedef _Float16 half8 __attribute__((ext_vector_type(8)));
typedef float f32x4 __attribute__((ext_vector_type(4)));

__device__ __forceinline__ void edge_sd(const int* __restrict__ ei, int e, int E, int& s, int& d) {
    if (e < E) { s = ei[e]; d = ei[E + e]; }
    else       { s = e - E; d = e - E; }   // self loops appended
}

// ---------------- CSR build: hist with rank capture, 4 edges/thread ----------------
__global__ void hist_k(const int* __restrict__ ei, int E, int Nn,
                       int* __restrict__ cnt, int* __restrict__ rank) {
    const int E4 = E >> 2;
    int tid = blockIdx.x * 256 + threadIdx.x;
    if (tid < E4) {
        int4 d4 = *(const int4*)&ei[E + tid * 4];
        int4 r;
        r.x = atomicAdd(&cnt[d4.x], 1);
        r.y = atomicAdd(&cnt[d4.y], 1);
        r.z = atomicAdd(&cnt[d4.z], 1);
        r.w = atomicAdd(&cnt[d4.w], 1);
        *(int4*)&rank[tid * 4] = r;
    } else {
        int i = tid - E4;                      // self loop for node i
        if (i < Nn) rank[E + i] = atomicAdd(&cnt[i], 1);
    }
}

__device__ __forceinline__ int wave_incl_scan(int x, int lane) {
#pragma unroll
    for (int off = 1; off < 64; off <<= 1) {
        int y = __shfl_up(x, off);
        if (lane >= off) x += y;
    }
    return x;
}

__global__ __launch_bounds__(1024) void scan_blk_k(const int* __restrict__ cnt,
                                                   int* __restrict__ rowptr,
                                                   int* __restrict__ part, int Nn) {
    __shared__ int wsum[16];
    const int t = threadIdx.x, lane = t & 63, w = t >> 6;
    const int i = blockIdx.x * 1024 + t;
    int v = (i < Nn) ? cnt[i] : 0;
    int sc = wave_incl_scan(v, lane);
    if (lane == 63) wsum[w] = sc;
    __syncthreads();
    if (w == 0 && lane < 16) {
        int x = wsum[lane];
#pragma unroll
        for (int off = 1; off < 16; off <<= 1) {
            int y = __shfl_up(x, off);
            if (lane >= off) x += y;
        }
        wsum[lane] = x;
    }
    __syncthreads();
    int excl = sc - v + (w ? wsum[w - 1] : 0);
    if (i < Nn) rowptr[i] = excl;
    if (t == 1023) part[blockIdx.x] = wsum[15];
}

__global__ __launch_bounds__(128) void scan_part_k(int* __restrict__ part, int nb) {
    __shared__ int sm[128];
    int t = threadIdx.x;
    int v = (t < nb) ? part[t] : 0;
    sm[t] = v; __syncthreads();
    for (int off = 1; off < 128; off <<= 1) {
        int add = (t >= off) ? sm[t - off] : 0;
        __syncthreads();
        sm[t] += add;
        __syncthreads();
    }
    if (t < nb) part[t] = sm[t] - v;
}

__global__ __launch_bounds__(1024) void scan_add_k(int* __restrict__ rowptr,
                                                   const int* __restrict__ part,
                                                   int Nn, int ET) {
    int i = blockIdx.x * 1024 + threadIdx.x;
    if (i < Nn) rowptr[i] += part[blockIdx.x];
    if (i == 0) rowptr[Nn] = ET;
}

// no atomic: pos = rowptr[d] + rank[e]; 4 edges/thread
__global__ void scatter_k(const int* __restrict__ ei, int E, int Nn,
                          const int* __restrict__ rowptr, const int* __restrict__ rank,
                          int* __restrict__ srcs) {
    const int E4 = E >> 2;
    int tid = blockIdx.x * 256 + threadIdx.x;
    if (tid < E4) {
        int4 s4 = *(const int4*)&ei[tid * 4];
        int4 d4 = *(const int4*)&ei[E + tid * 4];
        int4 r4 = *(const int4*)&rank[tid * 4];
        srcs[rowptr[d4.x] + r4.x] = s4.x;
        srcs[rowptr[d4.y] + r4.y] = s4.y;
        srcs[rowptr[d4.z] + r4.z] = s4.z;
        srcs[rowptr[d4.w] + r4.w] = s4.w;
    } else {
        int i = tid - E4;
        if (i < Nn) srcs[rowptr[i] + rank[E + i]] = i;
    }
}

// ---------------- W1 pack into MFMA B-fragment order, fp16 ----------------
__global__ void wpack1_k(const float* __restrict__ W1, _Float16* __restrict__ Wpk) {
    int g = blockIdx.x * 256 + threadIdx.x;
    if (g >= 4096) return;
    int t = g >> 9, s = (g >> 6) & 7, l = g & 63;
    int krow = s * 32 + ((l >> 4) << 3);
    int col = t * 16 + (l & 15);
    half8 v;
#pragma unroll
    for (int j = 0; j < 8; ++j) v[j] = (_Float16)W1[(size_t)(krow + j) * 128 + col];
    *(half8*)&Wpk[(size_t)g * 8] = v;
}

// ---------------- layer1 GEMM via MFMA + fused attention coefficients ----------------
__global__ __launch_bounds__(512) void gemm1_k(const float* __restrict__ x,
                                               const _Float16* __restrict__ Wpk,
                                               const float* __restrict__ att_s,
                                               const float* __restrict__ att_d,
                                               _Float16* __restrict__ h1,
                                               float* __restrict__ a1s,
                                               float* __restrict__ a1d, int Mt) {
    __shared__ __align__(16) _Float16 xs[32 * 256];   // 16 KB, XOR-swizzled
    const int t = threadIdx.x;
    const int l = t & 63;
    const int w = t >> 6;
    const int mstr = w >> 2;
    const int npair = w & 3;                // == head for this wave's 32 cols

    half8 bf0[8], bf1[8];
#pragma unroll
    for (int s = 0; s < 8; ++s) {
        bf0[s] = *(const half8*)&Wpk[(size_t)(((npair * 2 + 0) * 8 + s) * 64 + l) * 8];
        bf1[s] = *(const half8*)&Wpk[(size_t)(((npair * 2 + 1) * 8 + s) * 64 + l) * 8];
    }
    // per-lane att weights for cols (head*32 + (l&15)) and (+16)
    const float as0 = att_s[npair * 32 + (l & 15)];
    const float as1 = att_s[npair * 32 + 16 + (l & 15)];
    const float ad0 = att_d[npair * 32 + (l & 15)];
    const float ad1 = att_d[npair * 32 + 16 + (l & 15)];

    const int r = t >> 4;
    const int kc = t & 15;
    const int swz = (r & 7) << 4;
    const int arow = mstr * 16 + (l & 15);
    const int aswz = (arow & 7) << 4;
    const int abase = arow * 256;

    for (int mt = blockIdx.x; mt < Mt; mt += gridDim.x) {
        const int mBase = mt * 32;
        const float4* xrow = (const float4*)(x + (size_t)(mBase + r) * 256);
#pragma unroll
        for (int i = 0; i < 4; ++i) {
            float4 v = xrow[kc + i * 16];
            union { _Float16 h[4]; uint2 u; } cv;
            cv.h[0] = (_Float16)v.x; cv.h[1] = (_Float16)v.y;
            cv.h[2] = (_Float16)v.z; cv.h[3] = (_Float16)v.w;
            int kb = kc * 8 + i * 128;
            *(uint2*)&xs[r * 256 + ((kb ^ swz) >> 1)] = cv.u;
        }
        __syncthreads();
        f32x4 acc0 = {0.f, 0.f, 0.f, 0.f}, acc1 = {0.f, 0.f, 0.f, 0.f};
#pragma unroll
        for (int s = 0; s < 8; ++s) {
            int kb = s * 64 + ((l >> 4) << 4);
            half8 a = *(const half8*)&xs[abase + ((kb ^ aswz) >> 1)];
            acc0 = __builtin_amdgcn_mfma_f32_16x16x32_f16(a, bf0[s], acc0, 0, 0, 0);
            acc1 = __builtin_amdgcn_mfma_f32_16x16x32_f16(a, bf1[s], acc1, 0, 0, 0);
        }
        const int drow = mBase + mstr * 16 + ((l >> 4) << 2);
        const int dcol = npair * 32 + (l & 15);
#pragma unroll
        for (int rr = 0; rr < 4; ++rr) {
            h1[(size_t)(drow + rr) * 128 + dcol]      = (_Float16)acc0[rr];
            h1[(size_t)(drow + rr) * 128 + dcol + 16] = (_Float16)acc1[rr];
            // fused a-coef: dot over this head's 32 cols (16 lanes x 2 accs)
            float ps = acc0[rr] * as0 + acc1[rr] * as1;
            float pd = acc0[rr] * ad0 + acc1[rr] * ad1;
#pragma unroll
            for (int off = 1; off < 16; off <<= 1) {
                ps += __shfl_xor(ps, off);
                pd += __shfl_xor(pd, off);
            }
            if ((l & 15) == 0) {
                a1s[(drow + rr) * 4 + npair] = ps;
                a1d[(drow + rr) * 4 + npair] = pd;
            }
        }
        __syncthreads();
    }
}

// ---------------- layer1 fused: softmax + aggregate + bias + ELU + gemm2 + acoef2 ----
// one 64-lane wave per destination node (R5 structure)
__global__ __launch_bounds__(256) void agg1_k(const int* __restrict__ rowptr,
                                              const int* __restrict__ srcs,
                                              const float* __restrict__ a1s,
                                              const float* __restrict__ a1d,
                                              const __half* __restrict__ h1,
                                              const float* __restrict__ b1,
                                              const float* __restrict__ W2,
                                              const float* __restrict__ att_s2,
                                              const float* __restrict__ att_d2,
                                              __half* __restrict__ h2,
                                              float* __restrict__ a2s,
                                              float* __restrict__ a2d, int Nn) {
    __shared__ int   s_s[4][64];
    __shared__ float s_al[4][64][4];
    __shared__ float rowb[4][128];
    __shared__ float w2s[128 * 16];
    const int wv = threadIdx.x >> 6;
    const int lane = threadIdx.x & 63;
    const int n = blockIdx.x * 4 + wv;

    for (int i4 = threadIdx.x; i4 < 512; i4 += 256)
        *(float4*)&w2s[i4 * 4] = *(const float4*)&W2[i4 * 4];

    if (n < Nn) {
        const int beg = rowptr[n], end = rowptr[n + 1];
        const int cnt = end - beg;
        const float4 ad4 = ((const float4*)a1d)[n];

        int e = beg + lane;
        bool val = e < end;
        int sv = val ? srcs[e] : 0;
        float4 a = ((const float4*)a1s)[sv];
        float v0 = a.x + ad4.x, v1 = a.y + ad4.y, v2 = a.z + ad4.z, v3 = a.w + ad4.w;
        v0 = fmaxf(v0, LEAKY * v0); v1 = fmaxf(v1, LEAKY * v1);
        v2 = fmaxf(v2, LEAKY * v2); v3 = fmaxf(v3, LEAKY * v3);
        float al0 = val ? __expf(v0) : 0.0f, al1 = val ? __expf(v1) : 0.0f;
        float al2 = val ? __expf(v2) : 0.0f, al3 = val ? __expf(v3) : 0.0f;
        float t0 = al0, t1 = al1, t2 = al2, t3 = al3;
        for (int base = beg + 64; base < end; base += 64) {   // rare (deg>64)
            int ee = base + lane; bool vv = ee < end;
            int ss = vv ? srcs[ee] : 0;
            float4 aa = ((const float4*)a1s)[ss];
            float w0 = aa.x + ad4.x, w1 = aa.y + ad4.y, w2v = aa.z + ad4.z, w3 = aa.w + ad4.w;
            w0 = fmaxf(w0, LEAKY * w0); w1 = fmaxf(w1, LEAKY * w1);
            w2v = fmaxf(w2v, LEAKY * w2v); w3 = fmaxf(w3, LEAKY * w3);
            if (vv) { t0 += __expf(w0); t1 += __expf(w1); t2 += __expf(w2v); t3 += __expf(w3); }
        }
#pragma unroll
        for (int off = 1; off < 64; off <<= 1) {
            t0 += __shfl_xor(t0, off); t1 += __shfl_xor(t1, off);
            t2 += __shfl_xor(t2, off); t3 += __shfl_xor(t3, off);
        }
        const float i0 = 1.0f / (t0 + 1e-16f), i1 = 1.0f / (t1 + 1e-16f);
        const float i2 = 1.0f / (t2 + 1e-16f), i3 = 1.0f / (t3 + 1e-16f);

        const int hc = lane >> 4;
        float2 acc = make_float2(0.0f, 0.0f);
        const size_t lo = 2 * lane;

        s_s[wv][lane] = sv;
        s_al[wv][lane][0] = al0 * i0; s_al[wv][lane][1] = al1 * i1;
        s_al[wv][lane][2] = al2 * i2; s_al[wv][lane][3] = al3 * i3;
        int wcnt = cnt < 64 ? cnt : 64;
        int ko = 0;
        // 4-wide ILP: 4 independent h1-row gathers in flight
        for (; ko + 4 <= wcnt; ko += 4) {
            int s0 = s_s[wv][ko+0], s1 = s_s[wv][ko+1];
            int s2 = s_s[wv][ko+2], s3 = s_s[wv][ko+3];
            float p0 = s_al[wv][ko+0][hc], p1 = s_al[wv][ko+1][hc];
            float p2 = s_al[wv][ko+2][hc], p3 = s_al[wv][ko+3][hc];
            float2 g0 = __half22float2(*(const __half2*)&h1[(size_t)s0 * 128 + lo]);
            float2 g1 = __half22float2(*(const __half2*)&h1[(size_t)s1 * 128 + lo]);
            float2 g2 = __half22float2(*(const __half2*)&h1[(size_t)s2 * 128 + lo]);
            float2 g3 = __half22float2(*(const __half2*)&h1[(size_t)s3 * 128 + lo]);
            acc.x = fmaf(p0, g0.x, acc.x); acc.y = fmaf(p0, g0.y, acc.y);
            acc.x = fmaf(p1, g1.x, acc.x); acc.y = fmaf(p1, g1.y, acc.y);
            acc.x = fmaf(p2, g2.x, acc.x); acc.y = fmaf(p2, g2.y, acc.y);
            acc.x = fmaf(p3, g3.x, acc.x); acc.y = fmaf(p3, g3.y, acc.y);
        }
        for (; ko < wcnt; ++ko) {
            int s = s_s[wv][ko];
            float p = s_al[wv][ko][hc];
            float2 g = __half22float2(*(const __half2*)&h1[(size_t)s * 128 + lo]);
            acc.x = fmaf(p, g.x, acc.x); acc.y = fmaf(p, g.y, acc.y);
        }
        for (int base = beg + 64; base < end; base += 64) {   // rare
            int ee = base + lane; bool vv = ee < end;
            int ss = vv ? srcs[ee] : 0;
            float4 aa = ((const float4*)a1s)[ss];
            float w0 = aa.x + ad4.x, w1 = aa.y + ad4.y, w2v = aa.z + ad4.z, w3 = aa.w + ad4.w;
            w0 = fmaxf(w0, LEAKY * w0); w1 = fmaxf(w1, LEAKY * w1);
            w2v = fmaxf(w2v, LEAKY * w2v); w3 = fmaxf(w3, LEAKY * w3);
            s_s[wv][lane] = ss;
            s_al[wv][lane][0] = vv ? __expf(w0) * i0 : 0.0f;
            s_al[wv][lane][1] = vv ? __expf(w1) * i1 : 0.0f;
            s_al[wv][lane][2] = vv ? __expf(w2v) * i2 : 0.0f;
            s_al[wv][lane][3] = vv ? __expf(w3) * i3 : 0.0f;
            int wc = end - base; if (wc > 64) wc = 64;
            for (int k2 = 0; k2 < wc; ++k2) {
                int s = s_s[wv][k2];
                float p = s_al[wv][k2][hc];
                float2 g = __half22float2(*(const __half2*)&h1[(size_t)s * 128 + lo]);
                acc.x = fmaf(p, g.x, acc.x); acc.y = fmaf(p, g.y, acc.y);
            }
        }
        float2 bb = *(const float2*)&b1[2 * lane];
        float ox = acc.x + bb.x, oy = acc.y + bb.y;
        ox = ox > 0.0f ? ox : expm1f(ox);                 // ELU
        oy = oy > 0.0f ? oy : expm1f(oy);
        rowb[wv][2 * lane] = ox;
        rowb[wv][2 * lane + 1] = oy;
    }
    __syncthreads();
    if (n >= Nn) return;

    // fused layer2 GEMM row; k = kk*4+q ordering -> bank-conflict-free
    const int q = lane >> 4, j = lane & 15;
    const float* rb = rowb[wv];
    float part = 0.0f;
#pragma unroll
    for (int kk = 0; kk < 32; ++kk) {
        int k = kk * 4 + q;
        part = fmaf(rb[k], w2s[k * 16 + j], part);
    }
    part += __shfl_xor(part, 16);
    part += __shfl_xor(part, 32);
    float vs = part * att_s2[j];
    float vd = part * att_d2[j];
#pragma unroll
    for (int off = 1; off < 16; off <<= 1) {
        vs += __shfl_xor(vs, off);
        vd += __shfl_xor(vd, off);
    }
    if (lane < 16) h2[(size_t)n * 16 + j] = __float2half(part);
    if (lane == 0) { a2s[n] = vs; a2d[n] = vd; }
}

// ---------------- layer2 fused softmax + aggregate + bias ----------------
__global__ __launch_bounds__(256) void agg2_k(const int* __restrict__ rowptr,
                                              const int* __restrict__ srcs,
                                              const float* __restrict__ a2s,
                                              const float* __restrict__ a2d,
                                              const __half* __restrict__ h2,
                                              const float* __restrict__ b2,
                                              float* __restrict__ dout, int Nn) {
    __shared__ int   s_s[4][64];
    __shared__ float s_al[4][64];
    const int wv = threadIdx.x >> 6;
    const int lane = threadIdx.x & 63;
    const int n = blockIdx.x * 4 + wv;
    if (n >= Nn) return;
    const int beg = rowptr[n], end = rowptr[n + 1];
    const int cnt = end - beg;
    const float adn = a2d[n];

    int e = beg + lane;
    bool val = e < end;
    int sv = val ? srcs[e] : 0;
    float av = a2s[sv] + adn;
    av = fmaxf(av, LEAKY * av);
    float al = val ? __expf(av) : 0.0f;
    float ss = al;
    for (int base = beg + 64; base < end; base += 64) {
        int ee = base + lane; bool vv = ee < end;
        float aw = a2s[vv ? srcs[ee] : 0] + adn;
        aw = fmaxf(aw, LEAKY * aw);
        if (vv) ss += __expf(aw);
    }
#pragma unroll
    for (int off = 1; off < 64; off <<= 1) ss += __shfl_xor(ss, off);
    const float sinv = 1.0f / (ss + 1e-16f);

    const int eg = lane >> 4, j = lane & 15;
    float acc = 0.0f;
    s_s[wv][lane] = sv;
    s_al[wv][lane] = al * sinv;
    int wcnt = cnt < 64 ? cnt : 64;
    int ko = eg;
    for (; ko + 4 < wcnt; ko += 8) {        // 2-wide ILP per group
        int s0 = s_s[wv][ko], s1 = s_s[wv][ko + 4];
        float p0 = s_al[wv][ko], p1 = s_al[wv][ko + 4];
        float g0 = __half2float(h2[(size_t)s0 * 16 + j]);
        float g1 = __half2float(h2[(size_t)s1 * 16 + j]);
        acc = fmaf(p0, g0, acc);
        acc = fmaf(p1, g1, acc);
    }
    for (; ko < wcnt; ko += 4) {
        acc = fmaf(s_al[wv][ko], __half2float(h2[(size_t)s_s[wv][ko] * 16 + j]), acc);
    }
    for (int base = beg + 64; base < end; base += 64) {
        int ee = base + lane; bool vv = ee < end;
        int sn = vv ? srcs[ee] : 0;
        float aw = a2s[sn] + adn;
        aw = fmaxf(aw, LEAKY * aw);
        s_s[wv][lane] = sn;
        s_al[wv][lane] = vv ? __expf(aw) * sinv : 0.0f;
        int wc = end - base; if (wc > 64) wc = 64;
        for (int k2 = eg; k2 < wc; k2 += 4) {
            acc = fmaf(s_al[wv][k2], __half2float(h2[(size_t)s_s[wv][k2] * 16 + j]), acc);
        }
    }
    acc += __shfl_xor(acc, 16);
    acc += __shfl_xor(acc, 32);
    if (lane < 16) dout[(size_t)n * 16 + j] = acc + b2[j];
}

extern "C" void kernel_launch(void* const* d_in, const int* in_sizes, int n_in,
                              void* d_out, int out_size, void* d_ws, size_t ws_size,
                              hipStream_t stream) {
    const float* x      = (const float*)d_in[0];
    const int*   ei     = (const int*)d_in[1];
    const float* W1     = (const float*)d_in[2];
    const float* att_s1 = (const float*)d_in[3];
    const float* att_d1 = (const float*)d_in[4];
    const float* b1     = (const float*)d_in[5];
    const float* W2     = (const float*)d_in[6];
    const float* att_s2 = (const float*)d_in[7];
    const float* att_d2 = (const float*)d_in[8];
    const float* b2     = (const float*)d_in[9];
    float* dout = (float*)d_out;

    const int Nn = in_sizes[0] / 256;     // 100000
    const int E  = in_sizes[1] / 2;       // 1600000
    const int ET = E + Nn;

    char* p = (char*)d_ws;
    auto alloc = [&](size_t bytes) { char* r = p; p += (bytes + 255) & ~(size_t)255; return r; };
    _Float16* h1  = (_Float16*)alloc((size_t)Nn * 128 * 2);
    __half* h2    = (__half*)alloc((size_t)Nn * 16 * 2);
    _Float16* Wpk = (_Float16*)alloc(4096 * 8 * 2);
    float* a1s    = (float*)alloc((size_t)Nn * 4 * 4);
    float* a1d    = (float*)alloc((size_t)Nn * 4 * 4);
    float* a2s    = (float*)alloc((size_t)Nn * 4);
    float* a2d    = (float*)alloc((size_t)Nn * 4);
    int* rowptr   = (int*)alloc((size_t)(Nn + 1) * 4);
    int* cnt      = (int*)alloc((size_t)Nn * 4);
    int* rank     = (int*)alloc((size_t)ET * 4);
    int* part     = (int*)alloc(128 * 4);
    int* srcs     = (int*)alloc((size_t)ET * 4);

    const int nbScan = (Nn + 1023) / 1024;
    const int nBuild = (E / 4 + Nn + 255) / 256;

    // CSR build (rank-capture: scatter needs no atomics; 4 edges/thread)
    hipMemsetAsync(cnt, 0, (size_t)Nn * 4, stream);
    wpack1_k<<<dim3(16), dim3(256), 0, stream>>>(W1, Wpk);
    hist_k<<<dim3(nBuild), dim3(256), 0, stream>>>(ei, E, Nn, cnt, rank);
    scan_blk_k<<<dim3(nbScan), dim3(1024), 0, stream>>>(cnt, rowptr, part, Nn);
    scan_part_k<<<dim3(1), dim3(128), 0, stream>>>(part, nbScan);
    scan_add_k<<<dim3(nbScan), dim3(1024), 0, stream>>>(rowptr, part, Nn, ET);
    scatter_k<<<dim3(nBuild), dim3(256), 0, stream>>>(ei, E, Nn, rowptr, rank, srcs);
    // layer 1 GEMM + fused a-coefs
    gemm1_k<<<dim3(512), dim3(512), 0, stream>>>(x, Wpk, att_s1, att_d1, h1, a1s, a1d, Nn / 32);
    // fused agg1 + gemm2 + acoef2
    agg1_k<<<dim3((Nn + 3) / 4), dim3(256), 0, stream>>>(rowptr, srcs, a1s, a1d,
                                                         (const __half*)h1, b1,
                                                         W2, att_s2, att_d2,
                                                         h2, a2s, a2d, Nn);
    // layer 2 aggregation
    agg2_k<<<dim3((Nn + 3) / 4), dim3(256), 0, stream>>>(rowptr, srcs, a2s, a2d, h2, b2, dout, Nn);
}

// Round 9
// 277.915 us; speedup vs baseline: 1.3461x; 1.0082x over previous
//
#include <hip/hip_runtime.h>
#include <hip/hip_fp16.h>
#include <cfloat>
#include <cmath>

#define LEAKY 0.2f

typedef _Float16 half8 __attribute__((ext_vector_type(8)));
typedef float f32x4 __attribute__((ext_vector_type(4)));

__device__ __forceinline__ void edge_sd(const int* __restrict__ ei, int e, int E, int& s, int& d) {
    if (e < E) { s = ei[e]; d = ei[E + e]; }
    else       { s = e - E; d = e - E; }   // self loops appended
}

__device__ __forceinline__ int wave_incl_scan(int x, int lane) {
#pragma unroll
    for (int off = 1; off < 64; off <<= 1) {
        int y = __shfl_up(x, off);
        if (lane >= off) x += y;
    }
    return x;
}

__global__ __launch_bounds__(1024) void scan_blk_k(const int* __restrict__ cnt,
                                                   int* __restrict__ rowptr,
                                                   int* __restrict__ part, int Nn) {
    __shared__ int wsum[16];
    const int t = threadIdx.x, lane = t & 63, w = t >> 6;
    const int i = blockIdx.x * 1024 + t;
    int v = (i < Nn) ? cnt[i] : 0;
    int sc = wave_incl_scan(v, lane);
    if (lane == 63) wsum[w] = sc;
    __syncthreads();
    if (w == 0 && lane < 16) {
        int x = wsum[lane];
#pragma unroll
        for (int off = 1; off < 16; off <<= 1) {
            int y = __shfl_up(x, off);
            if (lane >= off) x += y;
        }
        wsum[lane] = x;
    }
    __syncthreads();
    int excl = sc - v + (w ? wsum[w - 1] : 0);
    if (i < Nn) rowptr[i] = excl;
    if (t == 1023) part[blockIdx.x] = wsum[15];
}

__global__ __launch_bounds__(128) void scan_part_k(int* __restrict__ part, int nb) {
    __shared__ int sm[128];
    int t = threadIdx.x;
    int v = (t < nb) ? part[t] : 0;
    sm[t] = v; __syncthreads();
    for (int off = 1; off < 128; off <<= 1) {
        int add = (t >= off) ? sm[t - off] : 0;
        __syncthreads();
        sm[t] += add;
        __syncthreads();
    }
    if (t < nb) part[t] = sm[t] - v;
}

__global__ __launch_bounds__(1024) void scan_add_k(int* __restrict__ rowptr,
                                                   const int* __restrict__ part,
                                                   int Nn, int ET) {
    int i = blockIdx.x * 1024 + threadIdx.x;
    if (i < Nn) rowptr[i] += part[blockIdx.x];
    if (i == 0) rowptr[Nn] = ET;
}

// no atomic: pos = rowptr[d] + rank[e]; 4 edges/thread
__global__ void scatter_k(const int* __restrict__ ei, int E, int Nn,
                          const int* __restrict__ rowptr, const int* __restrict__ rank,
                          int* __restrict__ srcs) {
    const int E4 = E >> 2;
    int tid = blockIdx.x * 256 + threadIdx.x;
    if (tid < E4) {
        int4 s4 = *(const int4*)&ei[tid * 4];
        int4 d4 = *(const int4*)&ei[E + tid * 4];
        int4 r4 = *(const int4*)&rank[tid * 4];
        srcs[rowptr[d4.x] + r4.x] = s4.x;
        srcs[rowptr[d4.y] + r4.y] = s4.y;
        srcs[rowptr[d4.z] + r4.z] = s4.z;
        srcs[rowptr[d4.w] + r4.w] = s4.w;
    } else {
        int i = tid - E4;
        if (i < Nn) srcs[rowptr[i] + rank[E + i]] = i;
    }
}

// ---------------- W1 pack into MFMA B-fragment order, fp16 ----------------
__global__ void wpack1_k(const float* __restrict__ W1, _Float16* __restrict__ Wpk) {
    int g = blockIdx.x * 256 + threadIdx.x;
    if (g >= 4096) return;
    int t = g >> 9, s = (g >> 6) & 7, l = g & 63;
    int krow = s * 32 + ((l >> 4) << 3);
    int col = t * 16 + (l & 15);
    half8 v;
#pragma unroll
    for (int j = 0; j < 8; ++j) v[j] = (_Float16)W1[(size_t)(krow + j) * 128 + col];
    *(half8*)&Wpk[(size_t)g * 8] = v;
}

// ---------------- FAT kernel: hist (blocks [0,nBuildF)) ∥ gemm1+acoef1 (rest) ----------------
#define GEMM_BLOCKS 1024
__global__ __launch_bounds__(512) void fat_k(const int* __restrict__ ei, int E, int Nn,
                                             int* __restrict__ cnt, int* __restrict__ rank,
                                             int nBuildF,
                                             const float* __restrict__ x,
                                             const _Float16* __restrict__ Wpk,
                                             const float* __restrict__ att_s,
                                             const float* __restrict__ att_d,
                                             _Float16* __restrict__ h1,
                                             float* __restrict__ a1s,
                                             float* __restrict__ a1d, int Mt) {
    __shared__ __align__(16) _Float16 xs[32 * 256];   // 16 KB, XOR-swizzled (gemm role)
    const int t = threadIdx.x;

    if ((int)blockIdx.x < nBuildF) {
        // ---------- histogram role: 4 edges/thread + self loops ----------
        const int E4 = E >> 2;
        int tid = blockIdx.x * 512 + t;
        if (tid < E4) {
            int4 d4 = *(const int4*)&ei[E + tid * 4];
            int4 r;
            r.x = atomicAdd(&cnt[d4.x], 1);
            r.y = atomicAdd(&cnt[d4.y], 1);
            r.z = atomicAdd(&cnt[d4.z], 1);
            r.w = atomicAdd(&cnt[d4.w], 1);
            *(int4*)&rank[tid * 4] = r;
        } else {
            int i = tid - E4;                      // self loop for node i
            if (i < Nn) rank[E + i] = atomicAdd(&cnt[i], 1);
        }
        return;
    }

    // ---------- gemm role ----------
    const int gb = blockIdx.x - nBuildF;
    const int l = t & 63;
    const int w = t >> 6;
    const int mstr = w >> 2;
    const int npair = w & 3;                // == head for this wave's 32 cols

    half8 bf0[8], bf1[8];
#pragma unroll
    for (int s = 0; s < 8; ++s) {
        bf0[s] = *(const half8*)&Wpk[(size_t)(((npair * 2 + 0) * 8 + s) * 64 + l) * 8];
        bf1[s] = *(const half8*)&Wpk[(size_t)(((npair * 2 + 1) * 8 + s) * 64 + l) * 8];
    }
    const float as0 = att_s[npair * 32 + (l & 15)];
    const float as1 = att_s[npair * 32 + 16 + (l & 15)];
    const float ad0 = att_d[npair * 32 + (l & 15)];
    const float ad1 = att_d[npair * 32 + 16 + (l & 15)];

    const int r = t >> 4;
    const int kc = t & 15;
    const int swz = (r & 7) << 4;
    const int arow = mstr * 16 + (l & 15);
    const int aswz = (arow & 7) << 4;
    const int abase = arow * 256;

    for (int mt = gb; mt < Mt; mt += GEMM_BLOCKS) {
        const int mBase = mt * 32;
        const float4* xrow = (const float4*)(x + (size_t)(mBase + r) * 256);
#pragma unroll
        for (int i = 0; i < 4; ++i) {
            float4 v = xrow[kc + i * 16];
            union { _Float16 h[4]; uint2 u; } cv;
            cv.h[0] = (_Float16)v.x; cv.h[1] = (_Float16)v.y;
            cv.h[2] = (_Float16)v.z; cv.h[3] = (_Float16)v.w;
            int kb = kc * 8 + i * 128;
            *(uint2*)&xs[r * 256 + ((kb ^ swz) >> 1)] = cv.u;
        }
        __syncthreads();
        f32x4 acc0 = {0.f, 0.f, 0.f, 0.f}, acc1 = {0.f, 0.f, 0.f, 0.f};
#pragma unroll
        for (int s = 0; s < 8; ++s) {
            int kb = s * 64 + ((l >> 4) << 4);
            half8 a = *(const half8*)&xs[abase + ((kb ^ aswz) >> 1)];
            acc0 = __builtin_amdgcn_mfma_f32_16x16x32_f16(a, bf0[s], acc0, 0, 0, 0);
            acc1 = __builtin_amdgcn_mfma_f32_16x16x32_f16(a, bf1[s], acc1, 0, 0, 0);
        }
        const int drow = mBase + mstr * 16 + ((l >> 4) << 2);
        const int dcol = npair * 32 + (l & 15);
#pragma unroll
        for (int rr = 0; rr < 4; ++rr) {
            h1[(size_t)(drow + rr) * 128 + dcol]      = (_Float16)acc0[rr];
            h1[(size_t)(drow + rr) * 128 + dcol + 16] = (_Float16)acc1[rr];
            float ps = acc0[rr] * as0 + acc1[rr] * as1;
            float pd = acc0[rr] * ad0 + acc1[rr] * ad1;
#pragma unroll
            for (int off = 1; off < 16; off <<= 1) {
                ps += __shfl_xor(ps, off);
                pd += __shfl_xor(pd, off);
            }
            if ((l & 15) == 0) {
                a1s[(drow + rr) * 4 + npair] = ps;
                a1d[(drow + rr) * 4 + npair] = pd;
            }
        }
        __syncthreads();
    }
}

// ---------------- layer1 fused: softmax + aggregate + bias + ELU + gemm2 + acoef2 ----
// one 64-lane wave per destination node (R5 structure)
__global__ __launch_bounds__(256) void agg1_k(const int* __restrict__ rowptr,
                                              const int* __restrict__ srcs,
                                              const float* __restrict__ a1s,
                                              const float* __restrict__ a1d,
                                              const __half* __restrict__ h1,
                                              const float* __restrict__ b1,
                                              const float* __restrict__ W2,
                                              const float* __restrict__ att_s2,
                                              const float* __restrict__ att_d2,
                                              __half* __restrict__ h2,
                                              float* __restrict__ a2s,
                                              float* __restrict__ a2d, int Nn) {
    __shared__ int   s_s[4][64];
    __shared__ float s_al[4][64][4];
    __shared__ float rowb[4][128];
    __shared__ float w2s[128 * 16];
    const int wv = threadIdx.x >> 6;
    const int lane = threadIdx.x & 63;
    const int n = blockIdx.x * 4 + wv;

    for (int i4 = threadIdx.x; i4 < 512; i4 += 256)
        *(float4*)&w2s[i4 * 4] = *(const float4*)&W2[i4 * 4];

    if (n < Nn) {
        const int beg = rowptr[n], end = rowptr[n + 1];
        const int cnt = end - beg;
        const float4 ad4 = ((const float4*)a1d)[n];

        int e = beg + lane;
        bool val = e < end;
        int sv = val ? srcs[e] : 0;
        float4 a = ((const float4*)a1s)[sv];
        float v0 = a.x + ad4.x, v1 = a.y + ad4.y, v2 = a.z + ad4.z, v3 = a.w + ad4.w;
        v0 = fmaxf(v0, LEAKY * v0); v1 = fmaxf(v1, LEAKY * v1);
        v2 = fmaxf(v2, LEAKY * v2); v3 = fmaxf(v3, LEAKY * v3);
        float al0 = val ? __expf(v0) : 0.0f, al1 = val ? __expf(v1) : 0.0f;
        float al2 = val ? __expf(v2) : 0.0f, al3 = val ? __expf(v3) : 0.0f;
        float t0 = al0, t1 = al1, t2 = al2, t3 = al3;
        for (int base = beg + 64; base < end; base += 64) {   // rare (deg>64)
            int ee = base + lane; bool vv = ee < end;
            int ss = vv ? srcs[ee] : 0;
            float4 aa = ((const float4*)a1s)[ss];
            float w0 = aa.x + ad4.x, w1 = aa.y + ad4.y, w2v = aa.z + ad4.z, w3 = aa.w + ad4.w;
            w0 = fmaxf(w0, LEAKY * w0); w1 = fmaxf(w1, LEAKY * w1);
            w2v = fmaxf(w2v, LEAKY * w2v); w3 = fmaxf(w3, LEAKY * w3);
            if (vv) { t0 += __expf(w0); t1 += __expf(w1); t2 += __expf(w2v); t3 += __expf(w3); }
        }
#pragma unroll
        for (int off = 1; off < 64; off <<= 1) {
            t0 += __shfl_xor(t0, off); t1 += __shfl_xor(t1, off);
            t2 += __shfl_xor(t2, off); t3 += __shfl_xor(t3, off);
        }
        const float i0 = 1.0f / (t0 + 1e-16f), i1 = 1.0f / (t1 + 1e-16f);
        const float i2 = 1.0f / (t2 + 1e-16f), i3 = 1.0f / (t3 + 1e-16f);

        const int hc = lane >> 4;
        float2 acc = make_float2(0.0f, 0.0f);
        const size_t lo = 2 * lane;

        s_s[wv][lane] = sv;
        s_al[wv][lane][0] = al0 * i0; s_al[wv][lane][1] = al1 * i1;
        s_al[wv][lane][2] = al2 * i2; s_al[wv][lane][3] = al3 * i3;
        int wcnt = cnt < 64 ? cnt : 64;
        int ko = 0;
        // 4-wide ILP: 4 independent h1-row gathers in flight
        for (; ko + 4 <= wcnt; ko += 4) {
            int s0 = s_s[wv][ko+0], s1 = s_s[wv][ko+1];
            int s2 = s_s[wv][ko+2], s3 = s_s[wv][ko+3];
            float p0 = s_al[wv][ko+0][hc], p1 = s_al[wv][ko+1][hc];
            float p2 = s_al[wv][ko+2][hc], p3 = s_al[wv][ko+3][hc];
            float2 g0 = __half22float2(*(const __half2*)&h1[(size_t)s0 * 128 + lo]);
            float2 g1 = __half22float2(*(const __half2*)&h1[(size_t)s1 * 128 + lo]);
            float2 g2 = __half22float2(*(const __half2*)&h1[(size_t)s2 * 128 + lo]);
            float2 g3 = __half22float2(*(const __half2*)&h1[(size_t)s3 * 128 + lo]);
            acc.x = fmaf(p0, g0.x, acc.x); acc.y = fmaf(p0, g0.y, acc.y);
            acc.x = fmaf(p1, g1.x, acc.x); acc.y = fmaf(p1, g1.y, acc.y);
            acc.x = fmaf(p2, g2.x, acc.x); acc.y = fmaf(p2, g2.y, acc.y);
            acc.x = fmaf(p3, g3.x, acc.x); acc.y = fmaf(p3, g3.y, acc.y);
        }
        for (; ko < wcnt; ++ko) {
            int s = s_s[wv][ko];
            float p = s_al[wv][ko][hc];
            float2 g = __half22float2(*(const __half2*)&h1[(size_t)s * 128 + lo]);
            acc.x = fmaf(p, g.x, acc.x); acc.y = fmaf(p, g.y, acc.y);
        }
        for (int base = beg + 64; base < end; base += 64) {   // rare
            int ee = base + lane; bool vv = ee < end;
            int ss = vv ? srcs[ee] : 0;
            float4 aa = ((const float4*)a1s)[ss];
            float w0 = aa.x + ad4.x, w1 = aa.y + ad4.y, w2v = aa.z + ad4.z, w3 = aa.w + ad4.w;
            w0 = fmaxf(w0, LEAKY * w0); w1 = fmaxf(w1, LEAKY * w1);
            w2v = fmaxf(w2v, LEAKY * w2v); w3 = fmaxf(w3, LEAKY * w3);
            s_s[wv][lane] = ss;
            s_al[wv][lane][0] = vv ? __expf(w0) * i0 : 0.0f;
            s_al[wv][lane][1] = vv ? __expf(w1) * i1 : 0.0f;
            s_al[wv][lane][2] = vv ? __expf(w2v) * i2 : 0.0f;
            s_al[wv][lane][3] = vv ? __expf(w3) * i3 : 0.0f;
            int wc = end - base; if (wc > 64) wc = 64;
            for (int k2 = 0; k2 < wc; ++k2) {
                int s = s_s[wv][k2];
                float p = s_al[wv][k2][hc];
                float2 g = __half22float2(*(const __half2*)&h1[(size_t)s * 128 + lo]);
                acc.x = fmaf(p, g.x, acc.x); acc.y = fmaf(p, g.y, acc.y);
            }
        }
        float2 bb = *(const float2*)&b1[2 * lane];
        float ox = acc.x + bb.x, oy = acc.y + bb.y;
        ox = ox > 0.0f ? ox : expm1f(ox);                 // ELU
        oy = oy > 0.0f ? oy : expm1f(oy);
        rowb[wv][2 * lane] = ox;
        rowb[wv][2 * lane + 1] = oy;
    }
    __syncthreads();
    if (n >= Nn) return;

    // fused layer2 GEMM row; k = kk*4+q ordering -> bank-conflict-free
    const int q = lane >> 4, j = lane & 15;
    const float* rb = rowb[wv];
    float part = 0.0f;
#pragma unroll
    for (int kk = 0; kk < 32; ++kk) {
        int k = kk * 4 + q;
        part = fmaf(rb[k], w2s[k * 16 + j], part);
    }
    part += __shfl_xor(part, 16);
    part += __shfl_xor(part, 32);
    float vs = part * att_s2[j];
    float vd = part * att_d2[j];
#pragma unroll
    for (int off = 1; off < 16; off <<= 1) {
        vs += __shfl_xor(vs, off);
        vd += __shfl_xor(vd, off);
    }
    if (lane < 16) h2[(size_t)n * 16 + j] = __float2half(part);
    if (lane == 0) { a2s[n] = vs; a2d[n] = vd; }
}

// ---------------- layer2 fused softmax + aggregate + bias ----------------
__global__ __launch_bounds__(256) void agg2_k(const int* __restrict__ rowptr,
                                              const int* __restrict__ srcs,
                                              const float* __restrict__ a2s,
                                              const float* __restrict__ a2d,
                                              const __half* __restrict__ h2,
                                              const float* __restrict__ b2,
                                              float* __restrict__ dout, int Nn) {
    __shared__ int   s_s[4][64];
    __shared__ float s_al[4][64];
    const int wv = threadIdx.x >> 6;
    const int lane = threadIdx.x & 63;
    const int n = blockIdx.x * 4 + wv;
    if (n >= Nn) return;
    const int beg = rowptr[n], end = rowptr[n + 1];
    const int cnt = end - beg;
    const float adn = a2d[n];

    int e = beg + lane;
    bool val = e < end;
    int sv = val ? srcs[e] : 0;
    float av = a2s[sv] + adn;
    av = fmaxf(av, LEAKY * av);
    float al = val ? __expf(av) : 0.0f;
    float ss = al;
    for (int base = beg + 64; base < end; base += 64) {
        int ee = base + lane; bool vv = ee < end;
        float aw = a2s[vv ? srcs[ee] : 0] + adn;
        aw = fmaxf(aw, LEAKY * aw);
        if (vv) ss += __expf(aw);
    }
#pragma unroll
    for (int off = 1; off < 64; off <<= 1) ss += __shfl_xor(ss, off);
    const float sinv = 1.0f / (ss + 1e-16f);

    const int eg = lane >> 4, j = lane & 15;
    float acc = 0.0f;
    s_s[wv][lane] = sv;
    s_al[wv][lane] = al * sinv;
    int wcnt = cnt < 64 ? cnt : 64;
    int ko = eg;
    for (; ko + 4 < wcnt; ko += 8) {        // 2-wide ILP per group
        int s0 = s_s[wv][ko], s1 = s_s[wv][ko + 4];
        float p0 = s_al[wv][ko], p1 = s_al[wv][ko + 4];
        float g0 = __half2float(h2[(size_t)s0 * 16 + j]);
        float g1 = __half2float(h2[(size_t)s1 * 16 + j]);
        acc = fmaf(p0, g0, acc);
        acc = fmaf(p1, g1, acc);
    }
    for (; ko < wcnt; ko += 4) {
        acc = fmaf(s_al[wv][ko], __half2float(h2[(size_t)s_s[wv][ko] * 16 + j]), acc);
    }
    for (int base = beg + 64; base < end; base += 64) {
        int ee = base + lane; bool vv = ee < end;
        int sn = vv ? srcs[ee] : 0;
        float aw = a2s[sn] + adn;
        aw = fmaxf(aw, LEAKY * aw);
        s_s[wv][lane] = sn;
        s_al[wv][lane] = vv ? __expf(aw) * sinv : 0.0f;
        int wc = end - base; if (wc > 64) wc = 64;
        for (int k2 = eg; k2 < wc; k2 += 4) {
            acc = fmaf(s_al[wv][k2], __half2float(h2[(size_t)s_s[wv][k2] * 16 + j]), acc);
        }
    }
    acc += __shfl_xor(acc, 16);
    acc += __shfl_xor(acc, 32);
    if (lane < 16) dout[(size_t)n * 16 + j] = acc + b2[j];
}

extern "C" void kernel_launch(void* const* d_in, const int* in_sizes, int n_in,
                              void* d_out, int out_size, void* d_ws, size_t ws_size,
                              hipStream_t stream) {
    const float* x      = (const float*)d_in[0];
    const int*   ei     = (const int*)d_in[1];
    const float* W1     = (const float*)d_in[2];
    const float* att_s1 = (const float*)d_in[3];
    const float* att_d1 = (const float*)d_in[4];
    const float* b1     = (const float*)d_in[5];
    const float* W2     = (const float*)d_in[6];
    const float* att_s2 = (const float*)d_in[7];
    const float* att_d2 = (const float*)d_in[8];
    const float* b2     = (const float*)d_in[9];
    float* dout = (float*)d_out;

    const int Nn = in_sizes[0] / 256;     // 100000
    const int E  = in_sizes[1] / 2;       // 1600000
    const int ET = E + Nn;

    char* p = (char*)d_ws;
    auto alloc = [&](size_t bytes) { char* r = p; p += (bytes + 255) & ~(size_t)255; return r; };
    _Float16* h1  = (_Float16*)alloc((size_t)Nn * 128 * 2);
    __half* h2    = (__half*)alloc((size_t)Nn * 16 * 2);
    _Float16* Wpk = (_Float16*)alloc(4096 * 8 * 2);
    float* a1s    = (float*)alloc((size_t)Nn * 4 * 4);
    float* a1d    = (float*)alloc((size_t)Nn * 4 * 4);
    float* a2s    = (float*)alloc((size_t)Nn * 4);
    float* a2d    = (float*)alloc((size_t)Nn * 4);
    int* rowptr   = (int*)alloc((size_t)(Nn + 1) * 4);
    int* cnt      = (int*)alloc((size_t)Nn * 4);
    int* rank     = (int*)alloc((size_t)ET * 4);
    int* part     = (int*)alloc(128 * 4);
    int* srcs     = (int*)alloc((size_t)ET * 4);

    const int nbScan = (Nn + 1023) / 1024;
    const int nBuildF = (E / 4 + Nn + 511) / 512;           // hist role blocks (512 thr)
    const int nBuild256 = (E / 4 + Nn + 255) / 256;         // scatter blocks

    // W1 pack (must precede fat kernel's gemm role)
    hipMemsetAsync(cnt, 0, (size_t)Nn * 4, stream);
    wpack1_k<<<dim3(16), dim3(256), 0, stream>>>(W1, Wpk);
    // FAT: hist ∥ gemm1(+fused acoef1)
    fat_k<<<dim3(nBuildF + GEMM_BLOCKS), dim3(512), 0, stream>>>(
        ei, E, Nn, cnt, rank, nBuildF,
        x, Wpk, att_s1, att_d1, h1, a1s, a1d, Nn / 32);
    // scan + scatter
    scan_blk_k<<<dim3(nbScan), dim3(1024), 0, stream>>>(cnt, rowptr, part, Nn);
    scan_part_k<<<dim3(1), dim3(128), 0, stream>>>(part, nbScan);
    scan_add_k<<<dim3(nbScan), dim3(1024), 0, stream>>>(rowptr, part, Nn, ET);
    scatter_k<<<dim3(nBuild256), dim3(256), 0, stream>>>(ei, E, Nn, rowptr, rank, srcs);
    // fused agg1 + gemm2 + acoef2
    agg1_k<<<dim3((Nn + 3) / 4), dim3(256), 0, stream>>>(rowptr, srcs, a1s, a1d,
                                                         (const __half*)h1, b1,
                                                         W2, att_s2, att_d2,
                                                         h2, a2s, a2d, Nn);
    // layer 2 aggregation
    agg2_k<<<dim3((Nn + 3) / 4), dim3(256), 0, stream>>>(rowptr, srcs, a2s, a2d, h2, b2, dout, Nn);
}

// Round 10
// 267.390 us; speedup vs baseline: 1.3991x; 1.0394x over previous
//
#include <hip/hip_runtime.h>
#include <hip/hip_fp16.h>
#include <cfloat>
#include <cmath>

#define LEAKY 0.2f

typedef _Float16 half8 __attribute__((ext_vector_type(8)));
typedef float f32x4 __attribute__((ext_vector_type(4)));

__device__ __forceinline__ int wave_incl_scan(int x, int lane) {
#pragma unroll
    for (int off = 1; off < 64; off <<= 1) {
        int y = __shfl_up(x, off);
        if (lane >= off) x += y;
    }
    return x;
}

__global__ __launch_bounds__(1024) void scan_blk_k(const int* __restrict__ cnt,
                                                   int* __restrict__ rowptr,
                                                   int* __restrict__ part, int Nn) {
    __shared__ int wsum[16];
    const int t = threadIdx.x, lane = t & 63, w = t >> 6;
    const int i = blockIdx.x * 1024 + t;
    int v = (i < Nn) ? cnt[i] : 0;
    int sc = wave_incl_scan(v, lane);
    if (lane == 63) wsum[w] = sc;
    __syncthreads();
    if (w == 0 && lane < 16) {
        int x = wsum[lane];
#pragma unroll
        for (int off = 1; off < 16; off <<= 1) {
            int y = __shfl_up(x, off);
            if (lane >= off) x += y;
        }
        wsum[lane] = x;
    }
    __syncthreads();
    int excl = sc - v + (w ? wsum[w - 1] : 0);
    if (i < Nn) rowptr[i] = excl;
    if (t == 1023) part[blockIdx.x] = wsum[15];
}

// adds global part-prefix (computed per-block via butterfly) to rowptr
__global__ __launch_bounds__(1024) void scan_add2_k(int* __restrict__ rowptr,
                                                    const int* __restrict__ part,
                                                    int Nn, int ET) {
    __shared__ int sprefix;
    const int t = threadIdx.x;
    if (t < 64) {
        int x = 0;
        for (int i = t; i < (int)blockIdx.x; i += 64) x += part[i];   // <=2 iters at nb<=98
#pragma unroll
        for (int off = 1; off < 64; off <<= 1) x += __shfl_xor(x, off);
        if (t == 0) sprefix = x;
    }
    __syncthreads();
    int i = blockIdx.x * 1024 + t;
    if (i < Nn) rowptr[i] += sprefix;
    if (i == 0) rowptr[Nn] = ET;
}

// no atomic: pos = rowptr[d] + rank[e]; 4 edges/thread
__global__ void scatter_k(const int* __restrict__ ei, int E, int Nn,
                          const int* __restrict__ rowptr, const int* __restrict__ rank,
                          int* __restrict__ srcs) {
    const int E4 = E >> 2;
    int tid = blockIdx.x * 256 + threadIdx.x;
    if (tid < E4) {
        int4 s4 = *(const int4*)&ei[tid * 4];
        int4 d4 = *(const int4*)&ei[E + tid * 4];
        int4 r4 = *(const int4*)&rank[tid * 4];
        srcs[rowptr[d4.x] + r4.x] = s4.x;
        srcs[rowptr[d4.y] + r4.y] = s4.y;
        srcs[rowptr[d4.z] + r4.z] = s4.z;
        srcs[rowptr[d4.w] + r4.w] = s4.w;
    } else {
        int i = tid - E4;
        if (i < Nn) srcs[rowptr[i] + rank[E + i]] = i;
    }
}

// ---------------- W1 pack into MFMA B-fragment order, fp16 ----------------
__global__ void wpack1_k(const float* __restrict__ W1, _Float16* __restrict__ Wpk) {
    int g = blockIdx.x * 256 + threadIdx.x;
    if (g >= 4096) return;
    int t = g >> 9, s = (g >> 6) & 7, l = g & 63;
    int krow = s * 32 + ((l >> 4) << 3);
    int col = t * 16 + (l & 15);
    half8 v;
#pragma unroll
    for (int j = 0; j < 8; ++j) v[j] = (_Float16)W1[(size_t)(krow + j) * 128 + col];
    *(half8*)&Wpk[(size_t)g * 8] = v;
}

// ---------------- FAT kernel: hist (blocks [0,nBuildF)) ∥ gemm1+acoef1 (rest) ----------------
#define GEMM_BLOCKS 1024
__global__ __launch_bounds__(512) void fat_k(const int* __restrict__ ei, int E, int Nn,
                                             int* __restrict__ cnt, int* __restrict__ rank,
                                             int nBuildF,
                                             const float* __restrict__ x,
                                             const _Float16* __restrict__ Wpk,
                                             const float* __restrict__ att_s,
                                             const float* __restrict__ att_d,
                                             _Float16* __restrict__ h1,
                                             float* __restrict__ a1s,
                                             float* __restrict__ a1d, int Mt) {
    __shared__ __align__(16) _Float16 xs[32 * 256];   // 16 KB, XOR-swizzled (gemm role)
    const int t = threadIdx.x;

    if ((int)blockIdx.x < nBuildF) {
        // ---------- histogram role: 4 edges/thread + self loops ----------
        const int E4 = E >> 2;
        int tid = blockIdx.x * 512 + t;
        if (tid < E4) {
            int4 d4 = *(const int4*)&ei[E + tid * 4];
            int4 r;
            r.x = atomicAdd(&cnt[d4.x], 1);
            r.y = atomicAdd(&cnt[d4.y], 1);
            r.z = atomicAdd(&cnt[d4.z], 1);
            r.w = atomicAdd(&cnt[d4.w], 1);
            *(int4*)&rank[tid * 4] = r;
        } else {
            int i = tid - E4;                      // self loop for node i
            if (i < Nn) rank[E + i] = atomicAdd(&cnt[i], 1);
        }
        return;
    }

    // ---------- gemm role ----------
    const int gb = blockIdx.x - nBuildF;
    const int l = t & 63;
    const int w = t >> 6;
    const int mstr = w >> 2;
    const int npair = w & 3;                // == head for this wave's 32 cols

    half8 bf0[8], bf1[8];
#pragma unroll
    for (int s = 0; s < 8; ++s) {
        bf0[s] = *(const half8*)&Wpk[(size_t)(((npair * 2 + 0) * 8 + s) * 64 + l) * 8];
        bf1[s] = *(const half8*)&Wpk[(size_t)(((npair * 2 + 1) * 8 + s) * 64 + l) * 8];
    }
    const float as0 = att_s[npair * 32 + (l & 15)];
    const float as1 = att_s[npair * 32 + 16 + (l & 15)];
    const float ad0 = att_d[npair * 32 + (l & 15)];
    const float ad1 = att_d[npair * 32 + 16 + (l & 15)];

    const int r = t >> 4;
    const int kc = t & 15;
    const int swz = (r & 7) << 4;
    const int arow = mstr * 16 + (l & 15);
    const int aswz = (arow & 7) << 4;
    const int abase = arow * 256;

    for (int mt = gb; mt < Mt; mt += GEMM_BLOCKS) {
        const int mBase = mt * 32;
        const float4* xrow = (const float4*)(x + (size_t)(mBase + r) * 256);
#pragma unroll
        for (int i = 0; i < 4; ++i) {
            float4 v = xrow[kc + i * 16];
            union { _Float16 h[4]; uint2 u; } cv;
            cv.h[0] = (_Float16)v.x; cv.h[1] = (_Float16)v.y;
            cv.h[2] = (_Float16)v.z; cv.h[3] = (_Float16)v.w;
            int kb = kc * 8 + i * 128;
            *(uint2*)&xs[r * 256 + ((kb ^ swz) >> 1)] = cv.u;
        }
        __syncthreads();
        f32x4 acc0 = {0.f, 0.f, 0.f, 0.f}, acc1 = {0.f, 0.f, 0.f, 0.f};
#pragma unroll
        for (int s = 0; s < 8; ++s) {
            int kb = s * 64 + ((l >> 4) << 4);
            half8 a = *(const half8*)&xs[abase + ((kb ^ aswz) >> 1)];
            acc0 = __builtin_amdgcn_mfma_f32_16x16x32_f16(a, bf0[s], acc0, 0, 0, 0);
            acc1 = __builtin_amdgcn_mfma_f32_16x16x32_f16(a, bf1[s], acc1, 0, 0, 0);
        }
        const int drow = mBase + mstr * 16 + ((l >> 4) << 2);
        const int dcol = npair * 32 + (l & 15);
#pragma unroll
        for (int rr = 0; rr < 4; ++rr) {
            h1[(size_t)(drow + rr) * 128 + dcol]      = (_Float16)acc0[rr];
            h1[(size_t)(drow + rr) * 128 + dcol + 16] = (_Float16)acc1[rr];
            float ps = acc0[rr] * as0 + acc1[rr] * as1;
            float pd = acc0[rr] * ad0 + acc1[rr] * ad1;
#pragma unroll
            for (int off = 1; off < 16; off <<= 1) {
                ps += __shfl_xor(ps, off);
                pd += __shfl_xor(pd, off);
            }
            if ((l & 15) == 0) {
                a1s[(drow + rr) * 4 + npair] = ps;
                a1d[(drow + rr) * 4 + npair] = pd;
            }
        }
        __syncthreads();
    }
}

// ---------------- layer1 fused: softmax + aggregate + bias + ELU + gemm2 + acoef2 ----
// one 64-lane wave per destination node (R5 structure)
__global__ __launch_bounds__(256) void agg1_k(const int* __restrict__ rowptr,
                                              const int* __restrict__ srcs,
                                              const float* __restrict__ a1s,
                                              const float* __restrict__ a1d,
                                              const __half* __restrict__ h1,
                                              const float* __restrict__ b1,
                                              const float* __restrict__ W2,
                                              const float* __restrict__ att_s2,
                                              const float* __restrict__ att_d2,
                                              __half* __restrict__ h2,
                                              float* __restrict__ a2s,
                                              float* __restrict__ a2d, int Nn) {
    __shared__ int   s_s[4][64];
    __shared__ float s_al[4][64][4];
    __shared__ float rowb[4][128];
    __shared__ float w2s[128 * 16];
    const int wv = threadIdx.x >> 6;
    const int lane = threadIdx.x & 63;
    const int n = blockIdx.x * 4 + wv;

    for (int i4 = threadIdx.x; i4 < 512; i4 += 256)
        *(float4*)&w2s[i4 * 4] = *(const float4*)&W2[i4 * 4];

    if (n < Nn) {
        const int beg = rowptr[n], end = rowptr[n + 1];
        const int cnt = end - beg;
        const float4 ad4 = ((const float4*)a1d)[n];

        int e = beg + lane;
        bool val = e < end;
        int sv = val ? srcs[e] : 0;
        float4 a = ((const float4*)a1s)[sv];
        float v0 = a.x + ad4.x, v1 = a.y + ad4.y, v2 = a.z + ad4.z, v3 = a.w + ad4.w;
        v0 = fmaxf(v0, LEAKY * v0); v1 = fmaxf(v1, LEAKY * v1);
        v2 = fmaxf(v2, LEAKY * v2); v3 = fmaxf(v3, LEAKY * v3);
        float al0 = val ? __expf(v0) : 0.0f, al1 = val ? __expf(v1) : 0.0f;
        float al2 = val ? __expf(v2) : 0.0f, al3 = val ? __expf(v3) : 0.0f;
        float t0 = al0, t1 = al1, t2 = al2, t3 = al3;
        for (int base = beg + 64; base < end; base += 64) {   // rare (deg>64)
            int ee = base + lane; bool vv = ee < end;
            int ss = vv ? srcs[ee] : 0;
            float4 aa = ((const float4*)a1s)[ss];
            float w0 = aa.x + ad4.x, w1 = aa.y + ad4.y, w2v = aa.z + ad4.z, w3 = aa.w + ad4.w;
            w0 = fmaxf(w0, LEAKY * w0); w1 = fmaxf(w1, LEAKY * w1);
            w2v = fmaxf(w2v, LEAKY * w2v); w3 = fmaxf(w3, LEAKY * w3);
            if (vv) { t0 += __expf(w0); t1 += __expf(w1); t2 += __expf(w2v); t3 += __expf(w3); }
        }
#pragma unroll
        for (int off = 1; off < 64; off <<= 1) {
            t0 += __shfl_xor(t0, off); t1 += __shfl_xor(t1, off);
            t2 += __shfl_xor(t2, off); t3 += __shfl_xor(t3, off);
        }
        const float i0 = 1.0f / (t0 + 1e-16f), i1 = 1.0f / (t1 + 1e-16f);
        const float i2 = 1.0f / (t2 + 1e-16f), i3 = 1.0f / (t3 + 1e-16f);

        const int hc = lane >> 4;
        float2 acc = make_float2(0.0f, 0.0f);
        const size_t lo = 2 * lane;

        s_s[wv][lane] = sv;
        s_al[wv][lane][0] = al0 * i0; s_al[wv][lane][1] = al1 * i1;
        s_al[wv][lane][2] = al2 * i2; s_al[wv][lane][3] = al3 * i3;
        int wcnt = cnt < 64 ? cnt : 64;
        int ko = 0;
        // 4-wide ILP: 4 independent h1-row gathers in flight
        for (; ko + 4 <= wcnt; ko += 4) {
            int s0 = s_s[wv][ko+0], s1 = s_s[wv][ko+1];
            int s2 = s_s[wv][ko+2], s3 = s_s[wv][ko+3];
            float p0 = s_al[wv][ko+0][hc], p1 = s_al[wv][ko+1][hc];
            float p2 = s_al[wv][ko+2][hc], p3 = s_al[wv][ko+3][hc];
            float2 g0 = __half22float2(*(const __half2*)&h1[(size_t)s0 * 128 + lo]);
            float2 g1 = __half22float2(*(const __half2*)&h1[(size_t)s1 * 128 + lo]);
            float2 g2 = __half22float2(*(const __half2*)&h1[(size_t)s2 * 128 + lo]);
            float2 g3 = __half22float2(*(const __half2*)&h1[(size_t)s3 * 128 + lo]);
            acc.x = fmaf(p0, g0.x, acc.x); acc.y = fmaf(p0, g0.y, acc.y);
            acc.x = fmaf(p1, g1.x, acc.x); acc.y = fmaf(p1, g1.y, acc.y);
            acc.x = fmaf(p2, g2.x, acc.x); acc.y = fmaf(p2, g2.y, acc.y);
            acc.x = fmaf(p3, g3.x, acc.x); acc.y = fmaf(p3, g3.y, acc.y);
        }
        for (; ko < wcnt; ++ko) {
            int s = s_s[wv][ko];
            float p = s_al[wv][ko][hc];
            float2 g = __half22float2(*(const __half2*)&h1[(size_t)s * 128 + lo]);
            acc.x = fmaf(p, g.x, acc.x); acc.y = fmaf(p, g.y, acc.y);
        }
        for (int base = beg + 64; base < end; base += 64) {   // rare
            int ee = base + lane; bool vv = ee < end;
            int ss = vv ? srcs[ee] : 0;
            float4 aa = ((const float4*)a1s)[ss];
            float w0 = aa.x + ad4.x, w1 = aa.y + ad4.y, w2v = aa.z + ad4.z, w3 = aa.w + ad4.w;
            w0 = fmaxf(w0, LEAKY * w0); w1 = fmaxf(w1, LEAKY * w1);
            w2v = fmaxf(w2v, LEAKY * w2v); w3 = fmaxf(w3, LEAKY * w3);
            s_s[wv][lane] = ss;
            s_al[wv][lane][0] = vv ? __expf(w0) * i0 : 0.0f;
            s_al[wv][lane][1] = vv ? __expf(w1) * i1 : 0.0f;
            s_al[wv][lane][2] = vv ? __expf(w2v) * i2 : 0.0f;
            s_al[wv][lane][3] = vv ? __expf(w3) * i3 : 0.0f;
            int wc = end - base; if (wc > 64) wc = 64;
            for (int k2 = 0; k2 < wc; ++k2) {
                int s = s_s[wv][k2];
                float p = s_al[wv][k2][hc];
                float2 g = __half22float2(*(const __half2*)&h1[(size_t)s * 128 + lo]);
                acc.x = fmaf(p, g.x, acc.x); acc.y = fmaf(p, g.y, acc.y);
            }
        }
        float2 bb = *(const float2*)&b1[2 * lane];
        float ox = acc.x + bb.x, oy = acc.y + bb.y;
        ox = ox > 0.0f ? ox : expm1f(ox);                 // ELU
        oy = oy > 0.0f ? oy : expm1f(oy);
        rowb[wv][2 * lane] = ox;
        rowb[wv][2 * lane + 1] = oy;
    }
    __syncthreads();
    if (n >= Nn) return;

    // fused layer2 GEMM row; k = kk*4+q ordering -> bank-conflict-free
    const int q = lane >> 4, j = lane & 15;
    const float* rb = rowb[wv];
    float part = 0.0f;
#pragma unroll
    for (int kk = 0; kk < 32; ++kk) {
        int k = kk * 4 + q;
        part = fmaf(rb[k], w2s[k * 16 + j], part);
    }
    part += __shfl_xor(part, 16);
    part += __shfl_xor(part, 32);
    float vs = part * att_s2[j];
    float vd = part * att_d2[j];
#pragma unroll
    for (int off = 1; off < 16; off <<= 1) {
        vs += __shfl_xor(vs, off);
        vd += __shfl_xor(vd, off);
    }
    if (lane < 16) h2[(size_t)n * 16 + j] = __float2half(part);
    if (lane == 0) { a2s[n] = vs; a2d[n] = vd; }
}

// ---------------- layer2 fused softmax + aggregate + bias ----------------
// 16 lanes per node: 4 nodes/wave, 16 nodes/block — full lane utilization at deg~17
__global__ __launch_bounds__(256) void agg2_k(const int* __restrict__ rowptr,
                                              const int* __restrict__ srcs,
                                              const float* __restrict__ a2s,
                                              const float* __restrict__ a2d,
                                              const __half* __restrict__ h2,
                                              const float* __restrict__ b2,
                                              float* __restrict__ dout, int Nn) {
    __shared__ int   s_s[4][4][16];
    __shared__ float s_al[4][4][16];
    const int wv = threadIdx.x >> 6;
    const int lane = threadIdx.x & 63;
    const int g = lane >> 4;               // node slot in wave
    const int j = lane & 15;               // column / edge slot
    const int n = (blockIdx.x * 4 + wv) * 4 + g;
    if (n >= Nn) return;                   // no block-level barriers below
    const int beg = rowptr[n], end = rowptr[n + 1];
    const int cnt = end - beg;
    const float adn = a2d[n];

    // window 0: lane j owns edge beg+j
    int e = beg + j;
    bool val = e < end;
    int sv = val ? srcs[e] : 0;
    float av = a2s[sv] + adn;
    av = fmaxf(av, LEAKY * av);
    float al = val ? __expf(av) : 0.0f;
    float ssum = al;
    for (int base = beg + 16; base < end; base += 16) {
        int ee = base + j; bool vv = ee < end;
        float aw = a2s[vv ? srcs[ee] : 0] + adn;
        aw = fmaxf(aw, LEAKY * aw);
        if (vv) ssum += __expf(aw);
    }
#pragma unroll
    for (int off = 1; off < 16; off <<= 1) ssum += __shfl_xor(ssum, off);
    const float sinv = 1.0f / (ssum + 1e-16f);

    s_s[wv][g][j] = sv;
    s_al[wv][g][j] = al * sinv;
    float acc = 0.0f;
    int wcnt = cnt < 16 ? cnt : 16;
    int ko = 0;
    for (; ko + 2 <= wcnt; ko += 2) {      // 2-wide ILP
        int s0 = s_s[wv][g][ko], s1 = s_s[wv][g][ko + 1];
        float p0 = s_al[wv][g][ko], p1 = s_al[wv][g][ko + 1];
        float g0 = __half2float(h2[(size_t)s0 * 16 + j]);
        float g1 = __half2float(h2[(size_t)s1 * 16 + j]);
        acc = fmaf(p0, g0, acc);
        acc = fmaf(p1, g1, acc);
    }
    if (ko < wcnt)
        acc = fmaf(s_al[wv][g][ko], __half2float(h2[(size_t)s_s[wv][g][ko] * 16 + j]), acc);
    for (int base = beg + 16; base < end; base += 16) {
        int ee = base + j; bool vv = ee < end;
        int sn = vv ? srcs[ee] : 0;
        float aw = a2s[sn] + adn;
        aw = fmaxf(aw, LEAKY * aw);
        s_s[wv][g][j] = sn;
        s_al[wv][g][j] = vv ? __expf(aw) * sinv : 0.0f;
        int wc = end - base; if (wc > 16) wc = 16;
        int k2 = 0;
        for (; k2 + 2 <= wc; k2 += 2) {
            int s0 = s_s[wv][g][k2], s1 = s_s[wv][g][k2 + 1];
            float p0 = s_al[wv][g][k2], p1 = s_al[wv][g][k2 + 1];
            float g0 = __half2float(h2[(size_t)s0 * 16 + j]);
            float g1 = __half2float(h2[(size_t)s1 * 16 + j]);
            acc = fmaf(p0, g0, acc);
            acc = fmaf(p1, g1, acc);
        }
        if (k2 < wc)
            acc = fmaf(s_al[wv][g][k2], __half2float(h2[(size_t)s_s[wv][g][k2] * 16 + j]), acc);
    }
    dout[(size_t)n * 16 + j] = acc + b2[j];
}

extern "C" void kernel_launch(void* const* d_in, const int* in_sizes, int n_in,
                              void* d_out, int out_size, void* d_ws, size_t ws_size,
                              hipStream_t stream) {
    const float* x      = (const float*)d_in[0];
    const int*   ei     = (const int*)d_in[1];
    const float* W1     = (const float*)d_in[2];
    const float* att_s1 = (const float*)d_in[3];
    const float* att_d1 = (const float*)d_in[4];
    const float* b1     = (const float*)d_in[5];
    const float* W2     = (const float*)d_in[6];
    const float* att_s2 = (const float*)d_in[7];
    const float* att_d2 = (const float*)d_in[8];
    const float* b2     = (const float*)d_in[9];
    float* dout = (float*)d_out;

    const int Nn = in_sizes[0] / 256;     // 100000
    const int E  = in_sizes[1] / 2;       // 1600000
    const int ET = E + Nn;

    char* p = (char*)d_ws;
    auto alloc = [&](size_t bytes) { char* r = p; p += (bytes + 255) & ~(size_t)255; return r; };
    _Float16* h1  = (_Float16*)alloc((size_t)Nn * 128 * 2);
    __half* h2    = (__half*)alloc((size_t)Nn * 16 * 2);
    _Float16* Wpk = (_Float16*)alloc(4096 * 8 * 2);
    float* a1s    = (float*)alloc((size_t)Nn * 4 * 4);
    float* a1d    = (float*)alloc((size_t)Nn * 4 * 4);
    float* a2s    = (float*)alloc((size_t)Nn * 4);
    float* a2d    = (float*)alloc((size_t)Nn * 4);
    int* rowptr   = (int*)alloc((size_t)(Nn + 1) * 4);
    int* cnt      = (int*)alloc((size_t)Nn * 4);
    int* rank     = (int*)alloc((size_t)ET * 4);
    int* part     = (int*)alloc(128 * 4);
    int* srcs     = (int*)alloc((size_t)ET * 4);

    const int nbScan = (Nn + 1023) / 1024;
    const int nBuildF = (E / 4 + Nn + 511) / 512;           // hist role blocks (512 thr)
    const int nBuild256 = (E / 4 + Nn + 255) / 256;         // scatter blocks

    hipMemsetAsync(cnt, 0, (size_t)Nn * 4, stream);
    wpack1_k<<<dim3(16), dim3(256), 0, stream>>>(W1, Wpk);
    // FAT: hist ∥ gemm1(+fused acoef1)
    fat_k<<<dim3(nBuildF + GEMM_BLOCKS), dim3(512), 0, stream>>>(
        ei, E, Nn, cnt, rank, nBuildF,
        x, Wpk, att_s1, att_d1, h1, a1s, a1d, Nn / 32);
    // scan (2 kernels) + scatter
    scan_blk_k<<<dim3(nbScan), dim3(1024), 0, stream>>>(cnt, rowptr, part, Nn);
    scan_add2_k<<<dim3(nbScan), dim3(1024), 0, stream>>>(rowptr, part, Nn, ET);
    scatter_k<<<dim3(nBuild256), dim3(256), 0, stream>>>(ei, E, Nn, rowptr, rank, srcs);
    // fused agg1 + gemm2 + acoef2
    agg1_k<<<dim3((Nn + 3) / 4), dim3(256), 0, stream>>>(rowptr, srcs, a1s, a1d,
                                                         (const __half*)h1, b1,
                                                         W2, att_s2, att_d2,
                                                         h2, a2s, a2d, Nn);
    // layer 2 aggregation (16 lanes/node)
    agg2_k<<<dim3((Nn + 15) / 16), dim3(256), 0, stream>>>(rowptr, srcs, a2s, a2d, h2, b2, dout, Nn);
}

// Round 12
// 266.745 us; speedup vs baseline: 1.4025x; 1.0024x over previous
//
#include <hip/hip_runtime.h>
#include <hip/hip_fp16.h>
#include <cfloat>
#include <cmath>

#define LEAKY 0.2f

typedef _Float16 half8 __attribute__((ext_vector_type(8)));
typedef float f32x4 __attribute__((ext_vector_type(4)));

__device__ __forceinline__ int wave_incl_scan(int x, int lane) {
#pragma unroll
    for (int off = 1; off < 64; off <<= 1) {
        int y = __shfl_up(x, off);
        if (lane >= off) x += y;
    }
    return x;
}

__global__ __launch_bounds__(1024) void scan_blk_k(const int* __restrict__ cnt,
                                                   int* __restrict__ rowptr,
                                                   int* __restrict__ part, int Nn) {
    __shared__ int wsum[16];
    const int t = threadIdx.x, lane = t & 63, w = t >> 6;
    const int i = blockIdx.x * 1024 + t;
    int v = (i < Nn) ? cnt[i] : 0;
    int sc = wave_incl_scan(v, lane);
    if (lane == 63) wsum[w] = sc;
    __syncthreads();
    if (w == 0 && lane < 16) {
        int x = wsum[lane];
#pragma unroll
        for (int off = 1; off < 16; off <<= 1) {
            int y = __shfl_up(x, off);
            if (lane >= off) x += y;
        }
        wsum[lane] = x;
    }
    __syncthreads();
    int excl = sc - v + (w ? wsum[w - 1] : 0);
    if (i < Nn) rowptr[i] = excl;
    if (t == 1023) part[blockIdx.x] = wsum[15];
}

// adds global part-prefix (computed per-block via butterfly) to rowptr
__global__ __launch_bounds__(1024) void scan_add2_k(int* __restrict__ rowptr,
                                                    const int* __restrict__ part,
                                                    int Nn, int ET) {
    __shared__ int sprefix;
    const int t = threadIdx.x;
    if (t < 64) {
        int x = 0;
        for (int i = t; i < (int)blockIdx.x; i += 64) x += part[i];   // <=2 iters at nb<=98
#pragma unroll
        for (int off = 1; off < 64; off <<= 1) x += __shfl_xor(x, off);
        if (t == 0) sprefix = x;
    }
    __syncthreads();
    int i = blockIdx.x * 1024 + t;
    if (i < Nn) rowptr[i] += sprefix;
    if (i == 0) rowptr[Nn] = ET;
}

// no atomic: pos = rowptr[d] + rank[e]; 4 edges/thread
__global__ void scatter_k(const int* __restrict__ ei, int E, int Nn,
                          const int* __restrict__ rowptr, const int* __restrict__ rank,
                          int* __restrict__ srcs) {
    const int E4 = E >> 2;
    int tid = blockIdx.x * 256 + threadIdx.x;
    if (tid < E4) {
        int4 s4 = *(const int4*)&ei[tid * 4];
        int4 d4 = *(const int4*)&ei[E + tid * 4];
        int4 r4 = *(const int4*)&rank[tid * 4];
        srcs[rowptr[d4.x] + r4.x] = s4.x;
        srcs[rowptr[d4.y] + r4.y] = s4.y;
        srcs[rowptr[d4.z] + r4.z] = s4.z;
        srcs[rowptr[d4.w] + r4.w] = s4.w;
    } else {
        int i = tid - E4;
        if (i < Nn) srcs[rowptr[i] + rank[E + i]] = i;
    }
}

// ---------------- W1 pack into MFMA B-fragment order, fp16 ----------------
__global__ void wpack1_k(const float* __restrict__ W1, _Float16* __restrict__ Wpk) {
    int g = blockIdx.x * 256 + threadIdx.x;
    if (g >= 4096) return;
    int t = g >> 9, s = (g >> 6) & 7, l = g & 63;
    int krow = s * 32 + ((l >> 4) << 3);
    int col = t * 16 + (l & 15);
    half8 v;
#pragma unroll
    for (int j = 0; j < 8; ++j) v[j] = (_Float16)W1[(size_t)(krow + j) * 128 + col];
    *(half8*)&Wpk[(size_t)g * 8] = v;
}

// ---------------- FAT kernel: hist (blocks [0,nBuildF)) ∥ gemm1+acoef1 (rest) ----------------
#define GEMM_BLOCKS 1024
__global__ __launch_bounds__(512) void fat_k(const int* __restrict__ ei, int E, int Nn,
                                             int* __restrict__ cnt, int* __restrict__ rank,
                                             int nBuildF,
                                             const float* __restrict__ x,
                                             const _Float16* __restrict__ Wpk,
                                             const float* __restrict__ att_s,
                                             const float* __restrict__ att_d,
                                             _Float16* __restrict__ h1,
                                             float* __restrict__ a1s,
                                             float* __restrict__ a1d, int Mt) {
    __shared__ __align__(16) _Float16 xs[32 * 256];   // 16 KB, XOR-swizzled (gemm role)
    const int t = threadIdx.x;

    if ((int)blockIdx.x < nBuildF) {
        // ---------- histogram role: 4 edges/thread + self loops ----------
        const int E4 = E >> 2;
        int tid = blockIdx.x * 512 + t;
        if (tid < E4) {
            int4 d4 = *(const int4*)&ei[E + tid * 4];
            int4 r;
            r.x = atomicAdd(&cnt[d4.x], 1);
            r.y = atomicAdd(&cnt[d4.y], 1);
            r.z = atomicAdd(&cnt[d4.z], 1);
            r.w = atomicAdd(&cnt[d4.w], 1);
            *(int4*)&rank[tid * 4] = r;
        } else {
            int i = tid - E4;                      // self loop for node i
            if (i < Nn) rank[E + i] = atomicAdd(&cnt[i], 1);
        }
        return;
    }

    // ---------- gemm role ----------
    const int gb = blockIdx.x - nBuildF;
    const int l = t & 63;
    const int w = t >> 6;
    const int mstr = w >> 2;
    const int npair = w & 3;                // == head for this wave's 32 cols

    half8 bf0[8], bf1[8];
#pragma unroll
    for (int s = 0; s < 8; ++s) {
        bf0[s] = *(const half8*)&Wpk[(size_t)(((npair * 2 + 0) * 8 + s) * 64 + l) * 8];
        bf1[s] = *(const half8*)&Wpk[(size_t)(((npair * 2 + 1) * 8 + s) * 64 + l) * 8];
    }
    const float as0 = att_s[npair * 32 + (l & 15)];
    const float as1 = att_s[npair * 32 + 16 + (l & 15)];
    const float ad0 = att_d[npair * 32 + (l & 15)];
    const float ad1 = att_d[npair * 32 + 16 + (l & 15)];

    const int r = t >> 4;
    const int kc = t & 15;
    const int swz = (r & 7) << 4;
    const int arow = mstr * 16 + (l & 15);
    const int aswz = (arow & 7) << 4;
    const int abase = arow * 256;

    for (int mt = gb; mt < Mt; mt += GEMM_BLOCKS) {
        const int mBase = mt * 32;
        const float4* xrow = (const float4*)(x + (size_t)(mBase + r) * 256);
#pragma unroll
        for (int i = 0; i < 4; ++i) {
            float4 v = xrow[kc + i * 16];
            union { _Float16 h[4]; uint2 u; } cv;
            cv.h[0] = (_Float16)v.x; cv.h[1] = (_Float16)v.y;
            cv.h[2] = (_Float16)v.z; cv.h[3] = (_Float16)v.w;
            int kb = kc * 8 + i * 128;
            *(uint2*)&xs[r * 256 + ((kb ^ swz) >> 1)] = cv.u;
        }
        __syncthreads();
        f32x4 acc0 = {0.f, 0.f, 0.f, 0.f}, acc1 = {0.f, 0.f, 0.f, 0.f};
#pragma unroll
        for (int s = 0; s < 8; ++s) {
            int kb = s * 64 + ((l >> 4) << 4);
            half8 a = *(const half8*)&xs[abase + ((kb ^ aswz) >> 1)];
            acc0 = __builtin_amdgcn_mfma_f32_16x16x32_f16(a, bf0[s], acc0, 0, 0, 0);
            acc1 = __builtin_amdgcn_mfma_f32_16x16x32_f16(a, bf1[s], acc1, 0, 0, 0);
        }
        const int drow = mBase + mstr * 16 + ((l >> 4) << 2);
        const int dcol = npair * 32 + (l & 15);
#pragma unroll
        for (int rr = 0; rr < 4; ++rr) {
            h1[(size_t)(drow + rr) * 128 + dcol]      = (_Float16)acc0[rr];
            h1[(size_t)(drow + rr) * 128 + dcol + 16] = (_Float16)acc1[rr];
            float ps = acc0[rr] * as0 + acc1[rr] * as1;
            float pd = acc0[rr] * ad0 + acc1[rr] * ad1;
#pragma unroll
            for (int off = 1; off < 16; off <<= 1) {
                ps += __shfl_xor(ps, off);
                pd += __shfl_xor(pd, off);
            }
            if ((l & 15) == 0) {
                a1s[(drow + rr) * 4 + npair] = ps;
                a1d[(drow + rr) * 4 + npair] = pd;
            }
        }
        __syncthreads();
    }
}

// ---------------- layer1 fused: softmax + aggregate + bias + ELU + gemm2 + acoef2 ----
// one 64-lane wave per destination node (R5 structure)
__global__ __launch_bounds__(256) void agg1_k(const int* __restrict__ rowptr,
                                              const int* __restrict__ srcs,
                                              const float* __restrict__ a1s,
                                              const float* __restrict__ a1d,
                                              const __half* __restrict__ h1,
                                              const float* __restrict__ b1,
                                              const float* __restrict__ W2,
                                              const float* __restrict__ att_s2,
                                              const float* __restrict__ att_d2,
                                              __half* __restrict__ h2,
                                              float* __restrict__ a2s,
                                              float* __restrict__ a2d, int Nn) {
    __shared__ int   s_s[4][64];
    __shared__ float s_al[4][64][4];
    __shared__ float rowb[4][128];
    __shared__ float w2s[128 * 16];
    const int wv = threadIdx.x >> 6;
    const int lane = threadIdx.x & 63;
    const int n = blockIdx.x * 4 + wv;

    for (int i4 = threadIdx.x; i4 < 512; i4 += 256)
        *(float4*)&w2s[i4 * 4] = *(const float4*)&W2[i4 * 4];

    if (n < Nn) {
        const int beg = rowptr[n], end = rowptr[n + 1];
        const int cnt = end - beg;
        const float4 ad4 = ((const float4*)a1d)[n];

        int e = beg + lane;
        bool val = e < end;
        int sv = val ? srcs[e] : 0;
        float4 a = ((const float4*)a1s)[sv];
        float v0 = a.x + ad4.x, v1 = a.y + ad4.y, v2 = a.z + ad4.z, v3 = a.w + ad4.w;
        v0 = fmaxf(v0, LEAKY * v0); v1 = fmaxf(v1, LEAKY * v1);
        v2 = fmaxf(v2, LEAKY * v2); v3 = fmaxf(v3, LEAKY * v3);
        float al0 = val ? __expf(v0) : 0.0f, al1 = val ? __expf(v1) : 0.0f;
        float al2 = val ? __expf(v2) : 0.0f, al3 = val ? __expf(v3) : 0.0f;
        float t0 = al0, t1 = al1, t2 = al2, t3 = al3;
        for (int base = beg + 64; base < end; base += 64) {   // rare (deg>64)
            int ee = base + lane; bool vv = ee < end;
            int ss = vv ? srcs[ee] : 0;
            float4 aa = ((const float4*)a1s)[ss];
            float w0 = aa.x + ad4.x, w1 = aa.y + ad4.y, w2v = aa.z + ad4.z, w3 = aa.w + ad4.w;
            w0 = fmaxf(w0, LEAKY * w0); w1 = fmaxf(w1, LEAKY * w1);
            w2v = fmaxf(w2v, LEAKY * w2v); w3 = fmaxf(w3, LEAKY * w3);
            if (vv) { t0 += __expf(w0); t1 += __expf(w1); t2 += __expf(w2v); t3 += __expf(w3); }
        }
#pragma unroll
        for (int off = 1; off < 64; off <<= 1) {
            t0 += __shfl_xor(t0, off); t1 += __shfl_xor(t1, off);
            t2 += __shfl_xor(t2, off); t3 += __shfl_xor(t3, off);
        }
        const float i0 = 1.0f / (t0 + 1e-16f), i1 = 1.0f / (t1 + 1e-16f);
        const float i2 = 1.0f / (t2 + 1e-16f), i3 = 1.0f / (t3 + 1e-16f);

        const int hc = lane >> 4;
        float2 acc = make_float2(0.0f, 0.0f);
        const size_t lo = 2 * lane;

        s_s[wv][lane] = sv;
        s_al[wv][lane][0] = al0 * i0; s_al[wv][lane][1] = al1 * i1;
        s_al[wv][lane][2] = al2 * i2; s_al[wv][lane][3] = al3 * i3;
        int wcnt = cnt < 64 ? cnt : 64;
        int ko = 0;
        // 4-wide ILP: 4 independent h1-row gathers in flight
        for (; ko + 4 <= wcnt; ko += 4) {
            int s0 = s_s[wv][ko+0], s1 = s_s[wv][ko+1];
            int s2 = s_s[wv][ko+2], s3 = s_s[wv][ko+3];
            float p0 = s_al[wv][ko+0][hc], p1 = s_al[wv][ko+1][hc];
            float p2 = s_al[wv][ko+2][hc], p3 = s_al[wv][ko+3][hc];
            float2 g0 = __half22float2(*(const __half2*)&h1[(size_t)s0 * 128 + lo]);
            float2 g1 = __half22float2(*(const __half2*)&h1[(size_t)s1 * 128 + lo]);
            float2 g2 = __half22float2(*(const __half2*)&h1[(size_t)s2 * 128 + lo]);
            float2 g3 = __half22float2(*(const __half2*)&h1[(size_t)s3 * 128 + lo]);
            acc.x = fmaf(p0, g0.x, acc.x); acc.y = fmaf(p0, g0.y, acc.y);
            acc.x = fmaf(p1, g1.x, acc.x); acc.y = fmaf(p1, g1.y, acc.y);
            acc.x = fmaf(p2, g2.x, acc.x); acc.y = fmaf(p2, g2.y, acc.y);
            acc.x = fmaf(p3, g3.x, acc.x); acc.y = fmaf(p3, g3.y, acc.y);
        }
        for (; ko < wcnt; ++ko) {
            int s = s_s[wv][ko];
            float p = s_al[wv][ko][hc];
            float2 g = __half22float2(*(const __half2*)&h1[(size_t)s * 128 + lo]);
            acc.x = fmaf(p, g.x, acc.x); acc.y = fmaf(p, g.y, acc.y);
        }
        for (int base = beg + 64; base < end; base += 64) {   // rare
            int ee = base + lane; bool vv = ee < end;
            int ss = vv ? srcs[ee] : 0;
            float4 aa = ((const float4*)a1s)[ss];
            float w0 = aa.x + ad4.x, w1 = aa.y + ad4.y, w2v = aa.z + ad4.z, w3 = aa.w + ad4.w;
            w0 = fmaxf(w0, LEAKY * w0); w1 = fmaxf(w1, LEAKY * w1);
            w2v = fmaxf(w2v, LEAKY * w2v); w3 = fmaxf(w3, LEAKY * w3);
            s_s[wv][lane] = ss;
            s_al[wv][lane][0] = vv ? __expf(w0) * i0 : 0.0f;
            s_al[wv][lane][1] = vv ? __expf(w1) * i1 : 0.0f;
            s_al[wv][lane][2] = vv ? __expf(w2v) * i2 : 0.0f;
            s_al[wv][lane][3] = vv ? __expf(w3) * i3 : 0.0f;
            int wc = end - base; if (wc > 64) wc = 64;
            for (int k2 = 0; k2 < wc; ++k2) {
                int s = s_s[wv][k2];
                float p = s_al[wv][k2][hc];
                float2 g = __half22float2(*(const __half2*)&h1[(size_t)s * 128 + lo]);
                acc.x = fmaf(p, g.x, acc.x); acc.y = fmaf(p, g.y, acc.y);
            }
        }
        float2 bb = *(const float2*)&b1[2 * lane];
        float ox = acc.x + bb.x, oy = acc.y + bb.y;
        ox = ox > 0.0f ? ox : expm1f(ox);                 // ELU
        oy = oy > 0.0f ? oy : expm1f(oy);
        rowb[wv][2 * lane] = ox;
        rowb[wv][2 * lane + 1] = oy;
    }
    __syncthreads();
    if (n >= Nn) return;

    // fused layer2 GEMM row; k = kk*4+q ordering -> bank-conflict-free
    const int q = lane >> 4, j = lane & 15;
    const float* rb = rowb[wv];
    float part = 0.0f;
#pragma unroll
    for (int kk = 0; kk < 32; ++kk) {
        int k = kk * 4 + q;
        part = fmaf(rb[k], w2s[k * 16 + j], part);
    }
    part += __shfl_xor(part, 16);
    part += __shfl_xor(part, 32);
    float vs = part * att_s2[j];
    float vd = part * att_d2[j];
#pragma unroll
    for (int off = 1; off < 16; off <<= 1) {
        vs += __shfl_xor(vs, off);
        vd += __shfl_xor(vd, off);
    }
    if (lane < 16) h2[(size_t)n * 16 + j] = __float2half(part);
    if (lane == 0) { a2s[n] = vs; a2d[n] = vd; }
}

// ---------------- layer2 fused softmax + aggregate + bias ----------------
// 16 lanes per node: 4 nodes/wave, 16 nodes/block — full lane utilization at deg~17
__global__ __launch_bounds__(256) void agg2_k(const int* __restrict__ rowptr,
                                              const int* __restrict__ srcs,
                                              const float* __restrict__ a2s,
                                              const float* __restrict__ a2d,
                                              const __half* __restrict__ h2,
                                              const float* __restrict__ b2,
                                              float* __restrict__ dout, int Nn) {
    __shared__ int   s_s[4][4][16];
    __shared__ float s_al[4][4][16];
    const int wv = threadIdx.x >> 6;
    const int lane = threadIdx.x & 63;
    const int g = lane >> 4;               // node slot in wave
    const int j = lane & 15;               // column / edge slot
    const int n = (blockIdx.x * 4 + wv) * 4 + g;
    if (n >= Nn) return;                   // no block-level barriers below
    const int beg = rowptr[n], end = rowptr[n + 1];
    const int cnt = end - beg;
    const float adn = a2d[n];

    // window 0: lane j owns edge beg+j
    int e = beg + j;
    bool val = e < end;
    int sv = val ? srcs[e] : 0;
    float av = a2s[sv] + adn;
    av = fmaxf(av, LEAKY * av);
    float al = val ? __expf(av) : 0.0f;
    float ssum = al;
    for (int base = beg + 16; base < end; base += 16) {
        int ee = base + j; bool vv = ee < end;
        float aw = a2s[vv ? srcs[ee] : 0] + adn;
        aw = fmaxf(aw, LEAKY * aw);
        if (vv) ssum += __expf(aw);
    }
#pragma unroll
    for (int off = 1; off < 16; off <<= 1) ssum += __shfl_xor(ssum, off);
    const float sinv = 1.0f / (ssum + 1e-16f);

    s_s[wv][g][j] = sv;
    s_al[wv][g][j] = al * sinv;
    float acc = 0.0f;
    int wcnt = cnt < 16 ? cnt : 16;
    int ko = 0;
    for (; ko + 2 <= wcnt; ko += 2) {      // 2-wide ILP
        int s0 = s_s[wv][g][ko], s1 = s_s[wv][g][ko + 1];
        float p0 = s_al[wv][g][ko], p1 = s_al[wv][g][ko + 1];
        float g0 = __half2float(h2[(size_t)s0 * 16 + j]);
        float g1 = __half2float(h2[(size_t)s1 * 16 + j]);
        acc = fmaf(p0, g0, acc);
        acc = fmaf(p1, g1, acc);
    }
    if (ko < wcnt)
        acc = fmaf(s_al[wv][g][ko], __half2float(h2[(size_t)s_s[wv][g][ko] * 16 + j]), acc);
    for (int base = beg + 16; base < end; base += 16) {
        int ee = base + j; bool vv = ee < end;
        int sn = vv ? srcs[ee] : 0;
        float aw = a2s[sn] + adn;
        aw = fmaxf(aw, LEAKY * aw);
        s_s[wv][g][j] = sn;
        s_al[wv][g][j] = vv ? __expf(aw) * sinv : 0.0f;
        int wc = end - base; if (wc > 16) wc = 16;
        int k2 = 0;
        for (; k2 + 2 <= wc; k2 += 2) {
            int s0 = s_s[wv][g][k2], s1 = s_s[wv][g][k2 + 1];
            float p0 = s_al[wv][g][k2], p1 = s_al[wv][g][k2 + 1];
            float g0 = __half2float(h2[(size_t)s0 * 16 + j]);
            float g1 = __half2float(h2[(size_t)s1 * 16 + j]);
            acc = fmaf(p0, g0, acc);
            acc = fmaf(p1, g1, acc);
        }
        if (k2 < wc)
            acc = fmaf(s_al[wv][g][k2], __half2float(h2[(size_t)s_s[wv][g][k2] * 16 + j]), acc);
    }
    dout[(size_t)n * 16 + j] = acc + b2[j];
}

extern "C" void kernel_launch(void* const* d_in, const int* in_sizes, int n_in,
                              void* d_out, int out_size, void* d_ws, size_t ws_size,
                              hipStream_t stream) {
    const float* x      = (const float*)d_in[0];
    const int*   ei     = (const int*)d_in[1];
    const float* W1     = (const float*)d_in[2];
    const float* att_s1 = (const float*)d_in[3];
    const float* att_d1 = (const float*)d_in[4];
    const float* b1     = (const float*)d_in[5];
    const float* W2     = (const float*)d_in[6];
    const float* att_s2 = (const float*)d_in[7];
    const float* att_d2 = (const float*)d_in[8];
    const float* b2     = (const float*)d_in[9];
    float* dout = (float*)d_out;

    const int Nn = in_sizes[0] / 256;     // 100000
    const int E  = in_sizes[1] / 2;       // 1600000
    const int ET = E + Nn;

    char* p = (char*)d_ws;
    auto alloc = [&](size_t bytes) { char* r = p; p += (bytes + 255) & ~(size_t)255; return r; };
    _Float16* h1  = (_Float16*)alloc((size_t)Nn * 128 * 2);
    __half* h2    = (__half*)alloc((size_t)Nn * 16 * 2);
    _Float16* Wpk = (_Float16*)alloc(4096 * 8 * 2);
    float* a1s    = (float*)alloc((size_t)Nn * 4 * 4);
    float* a1d    = (float*)alloc((size_t)Nn * 4 * 4);
    float* a2s    = (float*)alloc((size_t)Nn * 4);
    float* a2d    = (float*)alloc((size_t)Nn * 4);
    int* rowptr   = (int*)alloc((size_t)(Nn + 1) * 4);
    int* cnt      = (int*)alloc((size_t)Nn * 4);
    int* rank     = (int*)alloc((size_t)ET * 4);
    int* part     = (int*)alloc(128 * 4);
    int* srcs     = (int*)alloc((size_t)ET * 4);

    const int nbScan = (Nn + 1023) / 1024;
    const int nBuildF = (E / 4 + Nn + 511) / 512;           // hist role blocks (512 thr)
    const int nBuild256 = (E / 4 + Nn + 255) / 256;         // scatter blocks

    hipMemsetAsync(cnt, 0, (size_t)Nn * 4, stream);
    wpack1_k<<<dim3(16), dim3(256), 0, stream>>>(W1, Wpk);
    // FAT: hist ∥ gemm1(+fused acoef1)
    fat_k<<<dim3(nBuildF + GEMM_BLOCKS), dim3(512), 0, stream>>>(
        ei, E, Nn, cnt, rank, nBuildF,
        x, Wpk, att_s1, att_d1, h1, a1s, a1d, Nn / 32);
    // scan (2 kernels) + scatter
    scan_blk_k<<<dim3(nbScan), dim3(1024), 0, stream>>>(cnt, rowptr, part, Nn);
    scan_add2_k<<<dim3(nbScan), dim3(1024), 0, stream>>>(rowptr, part, Nn, ET);
    scatter_k<<<dim3(nBuild256), dim3(256), 0, stream>>>(ei, E, Nn, rowptr, rank, srcs);
    // fused agg1 + gemm2 + acoef2
    agg1_k<<<dim3((Nn + 3) / 4), dim3(256), 0, stream>>>(rowptr, srcs, a1s, a1d,
                                                         (const __half*)h1, b1,
                                                         W2, att_s2, att_d2,
                                                         h2, a2s, a2d, Nn);
    // layer 2 aggregation (16 lanes/node)
    agg2_k<<<dim3((Nn + 15) / 16), dim3(256), 0, stream>>>(rowptr, srcs, a2s, a2d, h2, b2, dout, Nn);
}